// Round 12
// baseline (1308.274 us; speedup 1.0000x reference)
//
#include <hip/hip_runtime.h>
#include <cstdint>
#include <cstddef>

typedef float f32x4 __attribute__((ext_vector_type(4)));
typedef float f32x16 __attribute__((ext_vector_type(16)));
typedef int i32x4 __attribute__((ext_vector_type(4)));
typedef int i32x8 __attribute__((ext_vector_type(8)));
typedef unsigned char u8;
typedef unsigned short u16;
typedef u16 u16x8 __attribute__((ext_vector_type(8)));

// ---------------- async global->LDS (16B per lane, linear dest) ----------------
static __device__ __forceinline__ void gload_lds16(const void* g, void* l) {
  __builtin_amdgcn_global_load_lds(
      (__attribute__((address_space(1))) void*)(void*)g,
      (__attribute__((address_space(3))) void*)l,
      16, 0, 0);
}

// ---------------- fp8 e4m3fn (OCP) conversion, RNE ----------------
#if defined(__has_builtin)
#if __has_builtin(__builtin_amdgcn_cvt_pk_fp8_f32)
#define HAVE_HW_FP8 1
#endif
#endif

__device__ __forceinline__ u8 f32_to_e4m3_sw(float x) {
  unsigned s = (__float_as_uint(x) >> 24) & 0x80;
  float ax = fabsf(x);
  if (!(ax > 0.0f)) return (u8)s;
  if (ax >= 448.0f) return (u8)(s | 0x7e);
  if (ax < 0.015625f) {            // subnormal, step 2^-9
    int m = (int)rintf(ax * 512.0f);
    if (m >= 8) return (u8)(s | 0x08);
    return (u8)(s | m);
  }
  int e = ilogbf(ax);
  int m = (int)rintf(ldexpf(ax, 3 - e));
  if (m == 16) { ++e; m = 8; }
  return (u8)(s | ((e + 7) << 3) | (m - 8));
}

__device__ __forceinline__ unsigned cvt4_fp8(float a, float b, float c, float d) {
#ifdef HAVE_HW_FP8
  int lo = __builtin_amdgcn_cvt_pk_fp8_f32(a, b, 0, false);
  return (unsigned)__builtin_amdgcn_cvt_pk_fp8_f32(c, d, lo, true);
#else
  return (unsigned)f32_to_e4m3_sw(a) | ((unsigned)f32_to_e4m3_sw(b) << 8) |
         ((unsigned)f32_to_e4m3_sw(c) << 16) | ((unsigned)f32_to_e4m3_sw(d) << 24);
#endif
}

__device__ __forceinline__ u16 f32_to_bf16(float x) {  // RNE
  unsigned u = __float_as_uint(x);
  return (u16)((u + 0x7FFFu + ((u >> 16) & 1u)) >> 16);
}

// ---------------- amax reduction (abs-max via unsigned-bits atomicMax) ----------------
__global__ __launch_bounds__(256) void amax_kernel(const float* __restrict__ src, size_t n4,
                                                   unsigned* __restrict__ out) {
  float m = 0.0f;
  size_t stride = (size_t)gridDim.x * blockDim.x;
  const f32x4* p = (const f32x4*)src;
  for (size_t i = (size_t)blockIdx.x * blockDim.x + threadIdx.x; i < n4; i += stride) {
    f32x4 v = p[i];
    m = fmaxf(m, fmaxf(fmaxf(fabsf(v[0]), fabsf(v[1])), fmaxf(fabsf(v[2]), fabsf(v[3]))));
  }
#pragma unroll
  for (int off = 32; off > 0; off >>= 1) m = fmaxf(m, __shfl_down(m, off));
  __shared__ float red[4];
  int lane = threadIdx.x & 63, wid = threadIdx.x >> 6;
  if (lane == 0) red[wid] = m;
  __syncthreads();
  if (threadIdx.x == 0) {
    float v = fmaxf(fmaxf(red[0], red[1]), fmaxf(red[2], red[3]));
    atomicMax(out, __float_as_uint(v));
  }
}

// ---------------- elementwise quantize f32 -> fp8 (8 elems/thread) ----------------
__global__ __launch_bounds__(256) void quant_kernel(const float* __restrict__ src,
                                                    u8* __restrict__ dst,
                                                    const unsigned* __restrict__ amax_bits,
                                                    size_t n8) {
  float amax = __uint_as_float(*amax_bits);
  float scale = 448.0f / fmaxf(amax, 1e-12f);
  size_t stride = (size_t)gridDim.x * blockDim.x;
  const f32x4* p = (const f32x4*)src;
  uint2* q = (uint2*)dst;
  for (size_t i = (size_t)blockIdx.x * blockDim.x + threadIdx.x; i < n8; i += stride) {
    f32x4 a = p[2 * i], b = p[2 * i + 1];
    float a0 = fminf(fmaxf(a[0] * scale, -448.f), 448.f);
    float a1 = fminf(fmaxf(a[1] * scale, -448.f), 448.f);
    float a2 = fminf(fmaxf(a[2] * scale, -448.f), 448.f);
    float a3 = fminf(fmaxf(a[3] * scale, -448.f), 448.f);
    float b0 = fminf(fmaxf(b[0] * scale, -448.f), 448.f);
    float b1 = fminf(fmaxf(b[1] * scale, -448.f), 448.f);
    float b2 = fminf(fmaxf(b[2] * scale, -448.f), 448.f);
    float b3 = fminf(fmaxf(b[3] * scale, -448.f), 448.f);
    uint2 r;
    r.x = cvt4_fp8(a0, a1, a2, a3);
    r.y = cvt4_fp8(b0, b1, b2, b3);
    q[i] = r;
  }
}

// ---------------- elementwise quantize bf16 -> fp8 (8 elems/thread) ----------------
__global__ __launch_bounds__(256) void quant_bf16_kernel(const u16* __restrict__ src,
                                                         u8* __restrict__ dst,
                                                         const unsigned* __restrict__ amax_bits,
                                                         size_t n8) {
  float amax = __uint_as_float(*amax_bits);
  float scale = 448.0f / fmaxf(amax, 1e-12f);
  size_t stride = (size_t)gridDim.x * blockDim.x;
  const u16x8* p = (const u16x8*)src;
  uint2* q = (uint2*)dst;
  for (size_t i = (size_t)blockIdx.x * blockDim.x + threadIdx.x; i < n8; i += stride) {
    u16x8 v = p[i];
    float f0 = __uint_as_float((unsigned)v[0] << 16) * scale;
    float f1 = __uint_as_float((unsigned)v[1] << 16) * scale;
    float f2 = __uint_as_float((unsigned)v[2] << 16) * scale;
    float f3 = __uint_as_float((unsigned)v[3] << 16) * scale;
    float f4 = __uint_as_float((unsigned)v[4] << 16) * scale;
    float f5 = __uint_as_float((unsigned)v[5] << 16) * scale;
    float f6 = __uint_as_float((unsigned)v[6] << 16) * scale;
    float f7 = __uint_as_float((unsigned)v[7] << 16) * scale;
    f0 = fminf(fmaxf(f0, -448.f), 448.f);
    f1 = fminf(fmaxf(f1, -448.f), 448.f);
    f2 = fminf(fmaxf(f2, -448.f), 448.f);
    f3 = fminf(fmaxf(f3, -448.f), 448.f);
    f4 = fminf(fmaxf(f4, -448.f), 448.f);
    f5 = fminf(fmaxf(f5, -448.f), 448.f);
    f6 = fminf(fmaxf(f6, -448.f), 448.f);
    f7 = fminf(fmaxf(f7, -448.f), 448.f);
    uint2 r;
    r.x = cvt4_fp8(f0, f1, f2, f3);
    r.y = cvt4_fp8(f4, f5, f6, f7);
    q[i] = r;
  }
}

// ---------------- transpose + quantize: src [R][C] f32 -> dst [C][R] fp8 ----------------
__global__ __launch_bounds__(256) void quantT_kernel(const float* __restrict__ src,
                                                     u8* __restrict__ dst,
                                                     const unsigned* __restrict__ amax_bits,
                                                     int R, int C) {
  __shared__ float t[64][65];
  float amax = __uint_as_float(*amax_bits);
  float scale = 448.0f / fmaxf(amax, 1e-12f);
  int nbr = R >> 6;
  int br = (int)blockIdx.x % nbr, bc = (int)blockIdx.x / nbr;
  int r0 = br * 64, c0 = bc * 64;
  int tid = threadIdx.x;
  int lc = tid & 63, lr = tid >> 6;
#pragma unroll
  for (int i = 0; i < 16; ++i)
    t[lr + i * 4][lc] = src[(size_t)(r0 + lr + i * 4) * C + c0 + lc];
  __syncthreads();
  int qd = tid & 15, xbase = tid >> 4;
#pragma unroll
  for (int i = 0; i < 4; ++i) {
    int x = xbase + 16 * i;  // output row index (column of src tile)
    float v0 = fminf(fmaxf(t[4 * qd + 0][x] * scale, -448.f), 448.f);
    float v1 = fminf(fmaxf(t[4 * qd + 1][x] * scale, -448.f), 448.f);
    float v2 = fminf(fmaxf(t[4 * qd + 2][x] * scale, -448.f), 448.f);
    float v3 = fminf(fmaxf(t[4 * qd + 3][x] * scale, -448.f), 448.f);
    *(unsigned*)(dst + (size_t)(c0 + x) * R + r0 + 4 * qd) = cvt4_fp8(v0, v1, v2, v3);
  }
}

// ---------------- LDS address swizzle ----------------
// 16B-block XOR within 64B row, key = (row>>2)&3 (verified conflict-free
// rounds 3/5/6/8/11: SQ_LDS_BANK_CONFLICT == 0).
__device__ __forceinline__ int swz_key(int r) { return (r >> 2) & 3; }

__device__ __forceinline__ int swz_off32(int r, int h) {
  return r * 64 + ((((h << 1) ^ swz_key(r)) << 4));
}

// Load a 32B MX-fp8 fragment (k-half h of row r) from a swizzled [*][64] tile.
__device__ __forceinline__ i32x8 ld_frag(const u8* base, int r, int h) {
  int o = swz_off32(r, h);
  i32x8 f;
  f.lo = *(const i32x4*)(base + o);
  f.hi = *(const i32x4*)(base + (o ^ 16));
  return f;
}

// Load a 32B MX-fp8 A-fragment straight from global (L2-resident panel).
__device__ __forceinline__ i32x8 ld_a_g(const u8* p) {
  i32x8 f;
  f.lo = *(const i32x4*)p;
  f.hi = *(const i32x4*)(p + 16);
  return f;
}

#define MFMA_MX(a, b, c) \
  __builtin_amdgcn_mfma_scale_f32_32x32x64_f8f6f4((a), (b), (c), 0, 0, 0, 0x7F7F7F7F, 0, 0x7F7F7F7F)

// ---------------- GEMM1: gate/up fused, NT, MX-fp8, 128x128, 4 waves ----------------
// r11 T3+T4 skeleton + A-FROM-GLOBAL: A-fragments are per-wave-private, so
// they bypass LDS entirely (global->VGPR, prefetched 1 K-step ahead in named
// regs). LDS traffic/block-step 72->48 KB. W/V keep gload_lds tri-buffer.
// vmcnt recount: 4 gload_lds per tile (W lo/hi, V lo/hi); per-iter VMEM
// issue order = [a(t+1) x4, stW(t+2) x2, stV(t+2) x2] = 8/iter ->
// at top of iter t, vmcnt(8) retires stV(t) (and older). B0 after it makes
// tile-t LDS visibility block-wide (round-9 lesson: vmcnt is per-wave).
// a-frags need no barrier (own-wave regs; compiler inserts its own vmcnt).
__global__ __launch_bounds__(256, 2) void gemm1_gateup(
    const u8* __restrict__ Aq, const u8* __restrict__ Wq, const u8* __restrict__ Vq,
    const unsigned* __restrict__ scal, u16* __restrict__ inter,
    unsigned* __restrict__ amax_mid, int M, int N, int K) {
  __shared__ __align__(16) u8 lW[3][8192], lV[3][8192];
  __shared__ float red[4];
  int tid = threadIdx.x;
  int lane = tid & 63, wid = tid >> 6;
  int wm = wid >> 1, wn = wid & 1;  // 2M x 2N waves, per-wave 64x64 dual

  int nbn = N >> 7;
  int nwg = (int)gridDim.x;
  int bid = (int)blockIdx.x;
  int cpx = nwg >> 3;
  int swz = (bid & 7) * cpx + (bid >> 3);  // nwg % 8 == 0
  int bm = swz / nbn, bn = swz - bm * nbn;

  int r0 = tid >> 2;                           // 0..63
  int kblk = ((tid & 3) ^ swz_key(r0)) << 4;   // pre-swizzled global source chunk
  const u8* wS = Wq + (size_t)(bn * 128 + r0) * K + kblk;
  const u8* vS = Vq + (size_t)(bn * 128 + r0) * K + kblk;
  size_t rK = (size_t)64 * K;                  // rows 64..127 (key period 16 -> same kblk)

  f32x16 g00 = (f32x16)(0.f), g01 = (f32x16)(0.f), g10 = (f32x16)(0.f), g11 = (f32x16)(0.f);
  f32x16 u00 = (f32x16)(0.f), u01 = (f32x16)(0.f), u10 = (f32x16)(0.f), u11 = (f32x16)(0.f);

  int rfrag = lane & 31;
  int h = lane >> 5;
  int arow = wm * 64 + rfrag;
  int brow = wn * 64 + rfrag;

  // per-lane global A pointers (natural layout, no swizzle)
  const u8* aG0 = Aq + (size_t)(bm * 128 + arow) * K + h * 32;
  const u8* aG1 = aG0 + (size_t)32 * K;

  int NT = K >> 6;
  // prologue: stage W/V tiles 0,1; load A-frags for tile 0 into regs
  {
    gload_lds16(wS + 0, lW[0] + tid * 16);
    gload_lds16(wS + 0 + rK, lW[0] + 4096 + tid * 16);
    gload_lds16(vS + 0, lV[0] + tid * 16);
    gload_lds16(vS + 0 + rK, lV[0] + 4096 + tid * 16);
    gload_lds16(wS + 64, lW[1] + tid * 16);
    gload_lds16(wS + 64 + rK, lW[1] + 4096 + tid * 16);
    gload_lds16(vS + 64, lV[1] + tid * 16);
    gload_lds16(vS + 64 + rK, lV[1] + 4096 + tid * 16);
  }
  i32x8 ac0 = ld_a_g(aG0), ac1 = ld_a_g(aG1);
  i32x8 an0 = ac0, an1 = ac1;

  for (int t = 0; t < NT; ++t) {
    int cur = t % 3;
    int nx = cur + 2; if (nx >= 3) nx -= 3;   // (t+2)%3
    int kt2 = (t + 2) * 64;
    bool do_stage = (t + 2) < NT;
    bool do_pref = (t + 1) < NT;
    if (do_pref) {
      asm volatile("s_waitcnt vmcnt(8)" ::: "memory");
    } else {
      asm volatile("s_waitcnt vmcnt(0)" ::: "memory");
    }
    __builtin_amdgcn_s_barrier();   // B0: tile t block-wide visible
    // ---- phase 0: gate ----
    i32x8 w0 = ld_frag(lW[cur], brow, h);
    i32x8 w1 = ld_frag(lW[cur], brow + 32, h);
    if (do_pref) {                  // A-frag prefetch for t+1 (own-wave regs)
      an0 = ld_a_g(aG0 + (t + 1) * 64);
      an1 = ld_a_g(aG1 + (t + 1) * 64);
    }
    if (do_stage) {
      gload_lds16(wS + kt2, lW[nx] + tid * 16);
      gload_lds16(wS + kt2 + rK, lW[nx] + 4096 + tid * 16);
    }
    __builtin_amdgcn_s_barrier();   // B1
    __builtin_amdgcn_s_setprio(1);
    g00 = MFMA_MX(ac0, w0, g00);
    g10 = MFMA_MX(ac1, w0, g10);
    g01 = MFMA_MX(ac0, w1, g01);
    g11 = MFMA_MX(ac1, w1, g11);
    __builtin_amdgcn_s_setprio(0);
    __builtin_amdgcn_s_barrier();   // B2
    // ---- phase 1: up ----
    i32x8 v0 = ld_frag(lV[cur], brow, h);
    i32x8 v1 = ld_frag(lV[cur], brow + 32, h);
    if (do_stage) {
      gload_lds16(vS + kt2, lV[nx] + tid * 16);
      gload_lds16(vS + kt2 + rK, lV[nx] + 4096 + tid * 16);
    }
    __builtin_amdgcn_s_barrier();   // B3
    __builtin_amdgcn_s_setprio(1);
    u00 = MFMA_MX(ac0, v0, u00);
    u10 = MFMA_MX(ac1, v0, u10);
    u01 = MFMA_MX(ac0, v1, u01);
    u11 = MFMA_MX(ac1, v1, u11);
    __builtin_amdgcn_s_setprio(0);
    ac0 = an0; ac1 = an1;           // advance A pipeline
    // next iteration's B0 doubles as the trailing barrier
  }

  float ax = __uint_as_float(scal[0]);
  float aw = __uint_as_float(scal[1]);
  float av = __uint_as_float(scal[2]);
  float inv_x = 1.0f / (448.0f / fmaxf(ax, 1e-12f));
  float inv_w = 1.0f / (448.0f / fmaxf(aw, 1e-12f));
  float inv_v = 1.0f / (448.0f / fmaxf(av, 1e-12f));
  float sg = inv_x * inv_w, su = inv_x * inv_v;

  // C/D layout 32x32: col = lane&31, row = (reg&3) + 8*(reg>>2) + 4*(lane>>5)
  int rb = bm * 128 + wm * 64 + h * 4;
  int cb = bn * 128 + wn * 64 + rfrag;
  float lmax = 0.0f;
#pragma unroll
  for (int mi = 0; mi < 2; ++mi)
#pragma unroll
    for (int ni = 0; ni < 2; ++ni) {
      const f32x16& gg = mi ? (ni ? g11 : g10) : (ni ? g01 : g00);
      const f32x16& uu = mi ? (ni ? u11 : u10) : (ni ? u01 : u00);
#pragma unroll
      for (int q = 0; q < 16; ++q) {
        int rr = rb + mi * 32 + (q & 3) + 8 * (q >> 2);
        float gv = gg[q] * sg;
        float uv = uu[q] * su;
        float iv = gv / (1.0f + expf(-gv)) * uv;  // silu(g)*u
        inter[(size_t)rr * N + (cb + ni * 32)] = f32_to_bf16(iv);
        lmax = fmaxf(lmax, fabsf(iv));
      }
    }
#pragma unroll
  for (int off = 32; off > 0; off >>= 1) lmax = fmaxf(lmax, __shfl_down(lmax, off));
  if (lane == 0) red[wid] = lmax;
  __syncthreads();
  if (tid == 0)
    atomicMax(amax_mid, __float_as_uint(fmaxf(fmaxf(red[0], red[1]), fmaxf(red[2], red[3]))));
}

// ---------------- GEMM2: down proj, NT vs pre-transposed w2, 128x128 ----------------
// Same skeleton: B (w2qT) via LDS tri-buffer (2 gload_lds/tile); A (midq)
// from global regs. Per-iter VMEM = [a(t+1) x4, stB(t+2) x2] = 6 -> vmcnt(6).
__global__ __launch_bounds__(256, 2) void gemm2_down(
    const u8* __restrict__ Aq, const u8* __restrict__ Bq,
    const unsigned* __restrict__ amax_a, const unsigned* __restrict__ amax_b,
    float* __restrict__ out, int M, int N, int K) {
  __shared__ __align__(16) u8 lB[3][8192];
  int tid = threadIdx.x;
  int lane = tid & 63, wid = tid >> 6;
  int wm = wid >> 1, wn = wid & 1;

  int nbn = N >> 7;
  int nwg = (int)gridDim.x;
  int bid = (int)blockIdx.x;
  int cpx = nwg >> 3;
  int swz = (bid & 7) * cpx + (bid >> 3);
  int bm = swz / nbn, bn = swz - bm * nbn;

  int r0 = tid >> 2;
  int kblk = ((tid & 3) ^ swz_key(r0)) << 4;
  const u8* bS = Bq + (size_t)(bn * 128 + r0) * K + kblk;
  size_t rK = (size_t)64 * K;

  f32x16 c00 = (f32x16)(0.f), c01 = (f32x16)(0.f);
  f32x16 c10 = (f32x16)(0.f), c11 = (f32x16)(0.f);

  int rfrag = lane & 31;
  int h = lane >> 5;
  int arow = wm * 64 + rfrag;
  int brow = wn * 64 + rfrag;

  const u8* aG0 = Aq + (size_t)(bm * 128 + arow) * K + h * 32;
  const u8* aG1 = aG0 + (size_t)32 * K;

  int NT = K >> 6;
  {
    gload_lds16(bS + 0, lB[0] + tid * 16);
    gload_lds16(bS + 0 + rK, lB[0] + 4096 + tid * 16);
    gload_lds16(bS + 64, lB[1] + tid * 16);
    gload_lds16(bS + 64 + rK, lB[1] + 4096 + tid * 16);
  }
  i32x8 ac0 = ld_a_g(aG0), ac1 = ld_a_g(aG1);
  i32x8 an0 = ac0, an1 = ac1;

  for (int t = 0; t < NT; ++t) {
    int cur = t % 3;
    int nx = cur + 2; if (nx >= 3) nx -= 3;
    int kt2 = (t + 2) * 64;
    bool do_stage = (t + 2) < NT;
    bool do_pref = (t + 1) < NT;
    if (do_pref) {
      asm volatile("s_waitcnt vmcnt(6)" ::: "memory");
    } else {
      asm volatile("s_waitcnt vmcnt(0)" ::: "memory");
    }
    __builtin_amdgcn_s_barrier();   // B0 (race fix)
    // ---- phase 0 ----
    i32x8 b0 = ld_frag(lB[cur], brow, h);
    if (do_pref) {
      an0 = ld_a_g(aG0 + (t + 1) * 64);
      an1 = ld_a_g(aG1 + (t + 1) * 64);
    }
    if (do_stage) {
      gload_lds16(bS + kt2, lB[nx] + tid * 16);
      gload_lds16(bS + kt2 + rK, lB[nx] + 4096 + tid * 16);
    }
    __builtin_amdgcn_s_barrier();
    __builtin_amdgcn_s_setprio(1);
    c00 = MFMA_MX(ac0, b0, c00);
    c10 = MFMA_MX(ac1, b0, c10);
    __builtin_amdgcn_s_setprio(0);
    __builtin_amdgcn_s_barrier();
    // ---- phase 1 ----
    i32x8 b1 = ld_frag(lB[cur], brow + 32, h);
    __builtin_amdgcn_s_barrier();
    __builtin_amdgcn_s_setprio(1);
    c01 = MFMA_MX(ac0, b1, c01);
    c11 = MFMA_MX(ac1, b1, c11);
    __builtin_amdgcn_s_setprio(0);
    ac0 = an0; ac1 = an1;
  }

  float sa = 1.0f / (448.0f / fmaxf(__uint_as_float(*amax_a), 1e-12f));
  float sb = 1.0f / (448.0f / fmaxf(__uint_as_float(*amax_b), 1e-12f));
  float sc = sa * sb;

  int rb = bm * 128 + wm * 64 + h * 4;
  int cb = bn * 128 + wn * 64 + rfrag;
#pragma unroll
  for (int mi = 0; mi < 2; ++mi)
#pragma unroll
    for (int ni = 0; ni < 2; ++ni) {
      const f32x16& cc = mi ? (ni ? c11 : c10) : (ni ? c01 : c00);
#pragma unroll
      for (int q = 0; q < 16; ++q) {
        int rr = rb + mi * 32 + (q & 3) + 8 * (q >> 2);
        out[(size_t)rr * N + (cb + ni * 32)] = cc[q] * sc;
      }
    }
}

// ---------------- host launcher ----------------
extern "C" void kernel_launch(void* const* d_in, const int* in_sizes, int n_in,
                              void* d_out, int out_size, void* d_ws, size_t ws_size,
                              hipStream_t stream) {
  const float* x  = (const float*)d_in[0];
  const float* w1 = (const float*)d_in[1];
  const float* v1 = (const float*)d_in[2];
  const float* w2 = (const float*)d_in[3];
  const int M = 4096, H = 4096, F = 10752;

  u8* ws = (u8*)d_ws;
  unsigned* scal = (unsigned*)ws;          // [0]=x [1]=w1 [2]=v1 [3]=w2 [4]=mid
  u8* xq   = ws + 256;
  u8* w1q  = xq   + (size_t)M * H;
  u8* v1q  = w1q  + (size_t)F * H;
  u8* w2qT = v1q  + (size_t)F * H;
  u8* midq = w2qT + (size_t)F * H;
  u16* inter = (u16*)(midq + (size_t)M * F);   // bf16 inter (halved traffic)

  hipMemsetAsync(scal, 0, 256, stream);
  amax_kernel<<<2048, 256, 0, stream>>>(x,  (size_t)M * H / 4, scal + 0);
  amax_kernel<<<2048, 256, 0, stream>>>(w1, (size_t)F * H / 4, scal + 1);
  amax_kernel<<<2048, 256, 0, stream>>>(v1, (size_t)F * H / 4, scal + 2);
  amax_kernel<<<2048, 256, 0, stream>>>(w2, (size_t)F * H / 4, scal + 3);

  quant_kernel<<<2048, 256, 0, stream>>>(x,  xq,  scal + 0, (size_t)M * H / 8);
  quant_kernel<<<2048, 256, 0, stream>>>(w1, w1q, scal + 1, (size_t)F * H / 8);
  quant_kernel<<<2048, 256, 0, stream>>>(v1, v1q, scal + 2, (size_t)F * H / 8);
  quantT_kernel<<<(F / 64) * (H / 64), 256, 0, stream>>>(w2, w2qT, scal + 3, F, H);

  gemm1_gateup<<<(M / 128) * (F / 128), 256, 0, stream>>>(xq, w1q, v1q, scal, inter,
                                                          scal + 4, M, F, H);
  quant_bf16_kernel<<<2048, 256, 0, stream>>>(inter, midq, scal + 4, (size_t)M * F / 8);
  gemm2_down<<<(M / 128) * (H / 128), 256, 0, stream>>>(midq, w2qT, scal + 4, scal + 3,
                                                        (float*)d_out, M, H, F);
}

// Round 13
// 1040.507 us; speedup vs baseline: 1.2573x; 1.2573x over previous
//
#include <hip/hip_runtime.h>
#include <cstdint>
#include <cstddef>

typedef float f32x4 __attribute__((ext_vector_type(4)));
typedef float f32x16 __attribute__((ext_vector_type(16)));
typedef int i32x4 __attribute__((ext_vector_type(4)));
typedef int i32x8 __attribute__((ext_vector_type(8)));
typedef unsigned char u8;
typedef unsigned short u16;
typedef u16 u16x8 __attribute__((ext_vector_type(8)));

// ---------------- async global->LDS (16B per lane, linear dest) ----------------
static __device__ __forceinline__ void gload_lds16(const void* g, void* l) {
  __builtin_amdgcn_global_load_lds(
      (__attribute__((address_space(1))) void*)(void*)g,
      (__attribute__((address_space(3))) void*)l,
      16, 0, 0);
}

// ---------------- fp8 e4m3fn (OCP) conversion, RNE ----------------
#if defined(__has_builtin)
#if __has_builtin(__builtin_amdgcn_cvt_pk_fp8_f32)
#define HAVE_HW_FP8 1
#endif
#endif

__device__ __forceinline__ u8 f32_to_e4m3_sw(float x) {
  unsigned s = (__float_as_uint(x) >> 24) & 0x80;
  float ax = fabsf(x);
  if (!(ax > 0.0f)) return (u8)s;
  if (ax >= 448.0f) return (u8)(s | 0x7e);
  if (ax < 0.015625f) {            // subnormal, step 2^-9
    int m = (int)rintf(ax * 512.0f);
    if (m >= 8) return (u8)(s | 0x08);
    return (u8)(s | m);
  }
  int e = ilogbf(ax);
  int m = (int)rintf(ldexpf(ax, 3 - e));
  if (m == 16) { ++e; m = 8; }
  return (u8)(s | ((e + 7) << 3) | (m - 8));
}

__device__ __forceinline__ unsigned cvt4_fp8(float a, float b, float c, float d) {
#ifdef HAVE_HW_FP8
  int lo = __builtin_amdgcn_cvt_pk_fp8_f32(a, b, 0, false);
  return (unsigned)__builtin_amdgcn_cvt_pk_fp8_f32(c, d, lo, true);
#else
  return (unsigned)f32_to_e4m3_sw(a) | ((unsigned)f32_to_e4m3_sw(b) << 8) |
         ((unsigned)f32_to_e4m3_sw(c) << 16) | ((unsigned)f32_to_e4m3_sw(d) << 24);
#endif
}

__device__ __forceinline__ u16 f32_to_bf16(float x) {  // RNE
  unsigned u = __float_as_uint(x);
  return (u16)((u + 0x7FFFu + ((u >> 16) & 1u)) >> 16);
}

// ---------------- amax reduction (abs-max via unsigned-bits atomicMax) ----------------
__global__ __launch_bounds__(256) void amax_kernel(const float* __restrict__ src, size_t n4,
                                                   unsigned* __restrict__ out) {
  float m = 0.0f;
  size_t stride = (size_t)gridDim.x * blockDim.x;
  const f32x4* p = (const f32x4*)src;
  for (size_t i = (size_t)blockIdx.x * blockDim.x + threadIdx.x; i < n4; i += stride) {
    f32x4 v = p[i];
    m = fmaxf(m, fmaxf(fmaxf(fabsf(v[0]), fabsf(v[1])), fmaxf(fabsf(v[2]), fabsf(v[3]))));
  }
#pragma unroll
  for (int off = 32; off > 0; off >>= 1) m = fmaxf(m, __shfl_down(m, off));
  __shared__ float red[4];
  int lane = threadIdx.x & 63, wid = threadIdx.x >> 6;
  if (lane == 0) red[wid] = m;
  __syncthreads();
  if (threadIdx.x == 0) {
    float v = fmaxf(fmaxf(red[0], red[1]), fmaxf(red[2], red[3]));
    atomicMax(out, __float_as_uint(v));
  }
}

// ---------------- elementwise quantize f32 -> fp8 (8 elems/thread) ----------------
__global__ __launch_bounds__(256) void quant_kernel(const float* __restrict__ src,
                                                    u8* __restrict__ dst,
                                                    const unsigned* __restrict__ amax_bits,
                                                    size_t n8) {
  float amax = __uint_as_float(*amax_bits);
  float scale = 448.0f / fmaxf(amax, 1e-12f);
  size_t stride = (size_t)gridDim.x * blockDim.x;
  const f32x4* p = (const f32x4*)src;
  uint2* q = (uint2*)dst;
  for (size_t i = (size_t)blockIdx.x * blockDim.x + threadIdx.x; i < n8; i += stride) {
    f32x4 a = p[2 * i], b = p[2 * i + 1];
    float a0 = fminf(fmaxf(a[0] * scale, -448.f), 448.f);
    float a1 = fminf(fmaxf(a[1] * scale, -448.f), 448.f);
    float a2 = fminf(fmaxf(a[2] * scale, -448.f), 448.f);
    float a3 = fminf(fmaxf(a[3] * scale, -448.f), 448.f);
    float b0 = fminf(fmaxf(b[0] * scale, -448.f), 448.f);
    float b1 = fminf(fmaxf(b[1] * scale, -448.f), 448.f);
    float b2 = fminf(fmaxf(b[2] * scale, -448.f), 448.f);
    float b3 = fminf(fmaxf(b[3] * scale, -448.f), 448.f);
    uint2 r;
    r.x = cvt4_fp8(a0, a1, a2, a3);
    r.y = cvt4_fp8(b0, b1, b2, b3);
    q[i] = r;
  }
}

// ---------------- elementwise quantize bf16 -> fp8 (8 elems/thread) ----------------
__global__ __launch_bounds__(256) void quant_bf16_kernel(const u16* __restrict__ src,
                                                         u8* __restrict__ dst,
                                                         const unsigned* __restrict__ amax_bits,
                                                         size_t n8) {
  float amax = __uint_as_float(*amax_bits);
  float scale = 448.0f / fmaxf(amax, 1e-12f);
  size_t stride = (size_t)gridDim.x * blockDim.x;
  const u16x8* p = (const u16x8*)src;
  uint2* q = (uint2*)dst;
  for (size_t i = (size_t)blockIdx.x * blockDim.x + threadIdx.x; i < n8; i += stride) {
    u16x8 v = p[i];
    float f0 = __uint_as_float((unsigned)v[0] << 16) * scale;
    float f1 = __uint_as_float((unsigned)v[1] << 16) * scale;
    float f2 = __uint_as_float((unsigned)v[2] << 16) * scale;
    float f3 = __uint_as_float((unsigned)v[3] << 16) * scale;
    float f4 = __uint_as_float((unsigned)v[4] << 16) * scale;
    float f5 = __uint_as_float((unsigned)v[5] << 16) * scale;
    float f6 = __uint_as_float((unsigned)v[6] << 16) * scale;
    float f7 = __uint_as_float((unsigned)v[7] << 16) * scale;
    f0 = fminf(fmaxf(f0, -448.f), 448.f);
    f1 = fminf(fmaxf(f1, -448.f), 448.f);
    f2 = fminf(fmaxf(f2, -448.f), 448.f);
    f3 = fminf(fmaxf(f3, -448.f), 448.f);
    f4 = fminf(fmaxf(f4, -448.f), 448.f);
    f5 = fminf(fmaxf(f5, -448.f), 448.f);
    f6 = fminf(fmaxf(f6, -448.f), 448.f);
    f7 = fminf(fmaxf(f7, -448.f), 448.f);
    uint2 r;
    r.x = cvt4_fp8(f0, f1, f2, f3);
    r.y = cvt4_fp8(f4, f5, f6, f7);
    q[i] = r;
  }
}

// ---------------- transpose + quantize: src [R][C] f32 -> dst [C][R] fp8 ----------------
__global__ __launch_bounds__(256) void quantT_kernel(const float* __restrict__ src,
                                                     u8* __restrict__ dst,
                                                     const unsigned* __restrict__ amax_bits,
                                                     int R, int C) {
  __shared__ float t[64][65];
  float amax = __uint_as_float(*amax_bits);
  float scale = 448.0f / fmaxf(amax, 1e-12f);
  int nbr = R >> 6;
  int br = (int)blockIdx.x % nbr, bc = (int)blockIdx.x / nbr;
  int r0 = br * 64, c0 = bc * 64;
  int tid = threadIdx.x;
  int lc = tid & 63, lr = tid >> 6;
#pragma unroll
  for (int i = 0; i < 16; ++i)
    t[lr + i * 4][lc] = src[(size_t)(r0 + lr + i * 4) * C + c0 + lc];
  __syncthreads();
  int qd = tid & 15, xbase = tid >> 4;
#pragma unroll
  for (int i = 0; i < 4; ++i) {
    int x = xbase + 16 * i;  // output row index (column of src tile)
    float v0 = fminf(fmaxf(t[4 * qd + 0][x] * scale, -448.f), 448.f);
    float v1 = fminf(fmaxf(t[4 * qd + 1][x] * scale, -448.f), 448.f);
    float v2 = fminf(fmaxf(t[4 * qd + 2][x] * scale, -448.f), 448.f);
    float v3 = fminf(fmaxf(t[4 * qd + 3][x] * scale, -448.f), 448.f);
    *(unsigned*)(dst + (size_t)(c0 + x) * R + r0 + 4 * qd) = cvt4_fp8(v0, v1, v2, v3);
  }
}

// ---------------- LDS address swizzle ----------------
// 16B-block XOR within 64B row, key = (row>>2)&3 (verified conflict-free
// rounds 3/5/6/8/11: SQ_LDS_BANK_CONFLICT == 0).
__device__ __forceinline__ int swz_key(int r) { return (r >> 2) & 3; }

__device__ __forceinline__ int swz_off32(int r, int h) {
  return r * 64 + ((((h << 1) ^ swz_key(r)) << 4));
}

// Load a 32B MX-fp8 fragment (k-half h of row r) from a swizzled [*][64] tile.
__device__ __forceinline__ i32x8 ld_frag(const u8* base, int r, int h) {
  int o = swz_off32(r, h);
  i32x8 f;
  f.lo = *(const i32x4*)(base + o);
  f.hi = *(const i32x4*)(base + (o ^ 16));
  return f;
}

#define MFMA_MX(a, b, c) \
  __builtin_amdgcn_mfma_scale_f32_32x32x64_f8f6f4((a), (b), (c), 0, 0, 0, 0x7F7F7F7F, 0, 0x7F7F7F7F)

// ---------------- GEMM1: gate/up fused, NT, MX-fp8, 128x128, 4 waves ----------------
// r11 structure EXACTLY (best measured: 456 us): A through LDS tri-buffer,
// counted vmcnt(6), B0 race-fix barrier after the wait. Only change vs r11:
// inter written as bf16 (RNE) — halves gemm1 write + quant-mid read.
// (r12's A-from-global REGRESSED: per-lane row-gather A loads split into 32
// L2 transactions each; gload_lds16's coalesced staging is strictly better.)
__global__ __launch_bounds__(256, 2) void gemm1_gateup(
    const u8* __restrict__ Aq, const u8* __restrict__ Wq, const u8* __restrict__ Vq,
    const unsigned* __restrict__ scal, u16* __restrict__ inter,
    unsigned* __restrict__ amax_mid, int M, int N, int K) {
  __shared__ __align__(16) u8 lA[3][8192], lW[3][8192], lV[3][8192];
  __shared__ float red[4];
  int tid = threadIdx.x;
  int lane = tid & 63, wid = tid >> 6;
  int wm = wid >> 1, wn = wid & 1;  // 2M x 2N waves, per-wave 64x64 dual

  int nbn = N >> 7;
  int nwg = (int)gridDim.x;
  int bid = (int)blockIdx.x;
  int cpx = nwg >> 3;
  int swz = (bid & 7) * cpx + (bid >> 3);  // nwg % 8 == 0
  int bm = swz / nbn, bn = swz - bm * nbn;

  int r0 = tid >> 2;                           // 0..63
  int kblk = ((tid & 3) ^ swz_key(r0)) << 4;   // pre-swizzled global source chunk
  const u8* aS = Aq + (size_t)(bm * 128 + r0) * K + kblk;
  const u8* wS = Wq + (size_t)(bn * 128 + r0) * K + kblk;
  const u8* vS = Vq + (size_t)(bn * 128 + r0) * K + kblk;
  size_t rK = (size_t)64 * K;                  // rows 64..127 (key period 16 -> same kblk)

  f32x16 g00 = (f32x16)(0.f), g01 = (f32x16)(0.f), g10 = (f32x16)(0.f), g11 = (f32x16)(0.f);
  f32x16 u00 = (f32x16)(0.f), u01 = (f32x16)(0.f), u10 = (f32x16)(0.f), u11 = (f32x16)(0.f);

  int rfrag = lane & 31;
  int h = lane >> 5;
  int arow = wm * 64 + rfrag;
  int brow = wn * 64 + rfrag;

  int NT = K >> 6;
  // prologue: stage tiles 0 and 1 (6 loads each)
  {
    gload_lds16(aS + 0, lA[0] + tid * 16);
    gload_lds16(aS + 0 + rK, lA[0] + 4096 + tid * 16);
    gload_lds16(wS + 0, lW[0] + tid * 16);
    gload_lds16(wS + 0 + rK, lW[0] + 4096 + tid * 16);
    gload_lds16(vS + 0, lV[0] + tid * 16);
    gload_lds16(vS + 0 + rK, lV[0] + 4096 + tid * 16);
    gload_lds16(aS + 64, lA[1] + tid * 16);
    gload_lds16(aS + 64 + rK, lA[1] + 4096 + tid * 16);
    gload_lds16(wS + 64, lW[1] + tid * 16);
    gload_lds16(wS + 64 + rK, lW[1] + 4096 + tid * 16);
    gload_lds16(vS + 64, lV[1] + tid * 16);
    gload_lds16(vS + 64 + rK, lV[1] + 4096 + tid * 16);
  }

  for (int t = 0; t < NT; ++t) {
    int cur = t % 3;
    int nx = cur + 2; if (nx >= 3) nx -= 3;   // (t+2)%3
    int kt2 = (t + 2) * 64;
    bool do_stage = (t + 2) < NT;
    // wait: OWN tile-t loads retired; B0 makes it block-wide before any read.
    if (t + 1 < NT) {
      asm volatile("s_waitcnt vmcnt(6)" ::: "memory");
    } else {
      asm volatile("s_waitcnt vmcnt(0)" ::: "memory");
    }
    __builtin_amdgcn_s_barrier();   // B0 (race fix)
    // ---- phase 0: gate ----
    i32x8 a0 = ld_frag(lA[cur], arow, h);
    i32x8 a1 = ld_frag(lA[cur], arow + 32, h);
    i32x8 w0 = ld_frag(lW[cur], brow, h);
    i32x8 w1 = ld_frag(lW[cur], brow + 32, h);
    if (do_stage) {
      gload_lds16(aS + kt2, lA[nx] + tid * 16);
      gload_lds16(aS + kt2 + rK, lA[nx] + 4096 + tid * 16);
      gload_lds16(wS + kt2, lW[nx] + tid * 16);
    }
    __builtin_amdgcn_s_barrier();   // B1
    __builtin_amdgcn_s_setprio(1);
    g00 = MFMA_MX(a0, w0, g00);
    g10 = MFMA_MX(a1, w0, g10);
    g01 = MFMA_MX(a0, w1, g01);
    g11 = MFMA_MX(a1, w1, g11);
    __builtin_amdgcn_s_setprio(0);
    __builtin_amdgcn_s_barrier();   // B2
    // ---- phase 1: up ----
    i32x8 v0 = ld_frag(lV[cur], brow, h);
    i32x8 v1 = ld_frag(lV[cur], brow + 32, h);
    if (do_stage) {
      gload_lds16(wS + kt2 + rK, lW[nx] + 4096 + tid * 16);
      gload_lds16(vS + kt2, lV[nx] + tid * 16);
      gload_lds16(vS + kt2 + rK, lV[nx] + 4096 + tid * 16);
    }
    __builtin_amdgcn_s_barrier();   // B3
    __builtin_amdgcn_s_setprio(1);
    u00 = MFMA_MX(a0, v0, u00);
    u10 = MFMA_MX(a1, v0, u10);
    u01 = MFMA_MX(a0, v1, u01);
    u11 = MFMA_MX(a1, v1, u11);
    __builtin_amdgcn_s_setprio(0);
    // next iteration's B0 doubles as the trailing barrier
  }

  float ax = __uint_as_float(scal[0]);
  float aw = __uint_as_float(scal[1]);
  float av = __uint_as_float(scal[2]);
  float inv_x = 1.0f / (448.0f / fmaxf(ax, 1e-12f));
  float inv_w = 1.0f / (448.0f / fmaxf(aw, 1e-12f));
  float inv_v = 1.0f / (448.0f / fmaxf(av, 1e-12f));
  float sg = inv_x * inv_w, su = inv_x * inv_v;

  // C/D layout 32x32: col = lane&31, row = (reg&3) + 8*(reg>>2) + 4*(lane>>5)
  int rb = bm * 128 + wm * 64 + h * 4;
  int cb = bn * 128 + wn * 64 + rfrag;
  float lmax = 0.0f;
#pragma unroll
  for (int mi = 0; mi < 2; ++mi)
#pragma unroll
    for (int ni = 0; ni < 2; ++ni) {
      const f32x16& gg = mi ? (ni ? g11 : g10) : (ni ? g01 : g00);
      const f32x16& uu = mi ? (ni ? u11 : u10) : (ni ? u01 : u00);
#pragma unroll
      for (int q = 0; q < 16; ++q) {
        int rr = rb + mi * 32 + (q & 3) + 8 * (q >> 2);
        float gv = gg[q] * sg;
        float uv = uu[q] * su;
        float iv = gv / (1.0f + expf(-gv)) * uv;  // silu(g)*u
        inter[(size_t)rr * N + (cb + ni * 32)] = f32_to_bf16(iv);
        lmax = fmaxf(lmax, fabsf(iv));
      }
    }
#pragma unroll
  for (int off = 32; off > 0; off >>= 1) lmax = fmaxf(lmax, __shfl_down(lmax, off));
  if (lane == 0) red[wid] = lmax;
  __syncthreads();
  if (tid == 0)
    atomicMax(amax_mid, __float_as_uint(fmaxf(fmaxf(red[0], red[1]), fmaxf(red[2], red[3]))));
}

// ---------------- GEMM2: down proj, NT vs pre-transposed w2, 128x128 ----------------
// r11 structure exactly: T3+T4 cadence + B0 race fix; 4 loads/stage -> vmcnt(4).
__global__ __launch_bounds__(256, 2) void gemm2_down(
    const u8* __restrict__ Aq, const u8* __restrict__ Bq,
    const unsigned* __restrict__ amax_a, const unsigned* __restrict__ amax_b,
    float* __restrict__ out, int M, int N, int K) {
  __shared__ __align__(16) u8 lA[3][8192], lB[3][8192];
  int tid = threadIdx.x;
  int lane = tid & 63, wid = tid >> 6;
  int wm = wid >> 1, wn = wid & 1;

  int nbn = N >> 7;
  int nwg = (int)gridDim.x;
  int bid = (int)blockIdx.x;
  int cpx = nwg >> 3;
  int swz = (bid & 7) * cpx + (bid >> 3);
  int bm = swz / nbn, bn = swz - bm * nbn;

  int r0 = tid >> 2;
  int kblk = ((tid & 3) ^ swz_key(r0)) << 4;
  const u8* aS = Aq + (size_t)(bm * 128 + r0) * K + kblk;
  const u8* bS = Bq + (size_t)(bn * 128 + r0) * K + kblk;
  size_t rK = (size_t)64 * K;

  f32x16 c00 = (f32x16)(0.f), c01 = (f32x16)(0.f);
  f32x16 c10 = (f32x16)(0.f), c11 = (f32x16)(0.f);

  int rfrag = lane & 31;
  int h = lane >> 5;
  int arow = wm * 64 + rfrag;
  int brow = wn * 64 + rfrag;

  int NT = K >> 6;
  {
    gload_lds16(aS + 0, lA[0] + tid * 16);
    gload_lds16(aS + 0 + rK, lA[0] + 4096 + tid * 16);
    gload_lds16(bS + 0, lB[0] + tid * 16);
    gload_lds16(bS + 0 + rK, lB[0] + 4096 + tid * 16);
    gload_lds16(aS + 64, lA[1] + tid * 16);
    gload_lds16(aS + 64 + rK, lA[1] + 4096 + tid * 16);
    gload_lds16(bS + 64, lB[1] + tid * 16);
    gload_lds16(bS + 64 + rK, lB[1] + 4096 + tid * 16);
  }

  for (int t = 0; t < NT; ++t) {
    int cur = t % 3;
    int nx = cur + 2; if (nx >= 3) nx -= 3;
    int kt2 = (t + 2) * 64;
    bool do_stage = (t + 2) < NT;
    if (t + 1 < NT) {
      asm volatile("s_waitcnt vmcnt(4)" ::: "memory");
    } else {
      asm volatile("s_waitcnt vmcnt(0)" ::: "memory");
    }
    __builtin_amdgcn_s_barrier();   // B0 (race fix)
    // ---- phase 0 ----
    i32x8 a0 = ld_frag(lA[cur], arow, h);
    i32x8 a1 = ld_frag(lA[cur], arow + 32, h);
    i32x8 b0 = ld_frag(lB[cur], brow, h);
    if (do_stage) {
      gload_lds16(aS + kt2, lA[nx] + tid * 16);
      gload_lds16(aS + kt2 + rK, lA[nx] + 4096 + tid * 16);
    }
    __builtin_amdgcn_s_barrier();
    __builtin_amdgcn_s_setprio(1);
    c00 = MFMA_MX(a0, b0, c00);
    c10 = MFMA_MX(a1, b0, c10);
    __builtin_amdgcn_s_setprio(0);
    __builtin_amdgcn_s_barrier();
    // ---- phase 1 ----
    i32x8 b1 = ld_frag(lB[cur], brow + 32, h);
    if (do_stage) {
      gload_lds16(bS + kt2, lB[nx] + tid * 16);
      gload_lds16(bS + kt2 + rK, lB[nx] + 4096 + tid * 16);
    }
    __builtin_amdgcn_s_barrier();
    __builtin_amdgcn_s_setprio(1);
    c01 = MFMA_MX(a0, b1, c01);
    c11 = MFMA_MX(a1, b1, c11);
    __builtin_amdgcn_s_setprio(0);
  }

  float sa = 1.0f / (448.0f / fmaxf(__uint_as_float(*amax_a), 1e-12f));
  float sb = 1.0f / (448.0f / fmaxf(__uint_as_float(*amax_b), 1e-12f));
  float sc = sa * sb;

  int rb = bm * 128 + wm * 64 + h * 4;
  int cb = bn * 128 + wn * 64 + rfrag;
#pragma unroll
  for (int mi = 0; mi < 2; ++mi)
#pragma unroll
    for (int ni = 0; ni < 2; ++ni) {
      const f32x16& cc = mi ? (ni ? c11 : c10) : (ni ? c01 : c00);
#pragma unroll
      for (int q = 0; q < 16; ++q) {
        int rr = rb + mi * 32 + (q & 3) + 8 * (q >> 2);
        out[(size_t)rr * N + (cb + ni * 32)] = cc[q] * sc;
      }
    }
}

// ---------------- host launcher ----------------
extern "C" void kernel_launch(void* const* d_in, const int* in_sizes, int n_in,
                              void* d_out, int out_size, void* d_ws, size_t ws_size,
                              hipStream_t stream) {
  const float* x  = (const float*)d_in[0];
  const float* w1 = (const float*)d_in[1];
  const float* v1 = (const float*)d_in[2];
  const float* w2 = (const float*)d_in[3];
  const int M = 4096, H = 4096, F = 10752;

  u8* ws = (u8*)d_ws;
  unsigned* scal = (unsigned*)ws;          // [0]=x [1]=w1 [2]=v1 [3]=w2 [4]=mid
  u8* xq   = ws + 256;
  u8* w1q  = xq   + (size_t)M * H;
  u8* v1q  = w1q  + (size_t)F * H;
  u8* w2qT = v1q  + (size_t)F * H;
  u8* midq = w2qT + (size_t)F * H;
  u16* inter = (u16*)(midq + (size_t)M * F);   // bf16 inter (halved traffic)

  hipMemsetAsync(scal, 0, 256, stream);
  amax_kernel<<<2048, 256, 0, stream>>>(x,  (size_t)M * H / 4, scal + 0);
  amax_kernel<<<2048, 256, 0, stream>>>(w1, (size_t)F * H / 4, scal + 1);
  amax_kernel<<<2048, 256, 0, stream>>>(v1, (size_t)F * H / 4, scal + 2);
  amax_kernel<<<2048, 256, 0, stream>>>(w2, (size_t)F * H / 4, scal + 3);

  quant_kernel<<<2048, 256, 0, stream>>>(x,  xq,  scal + 0, (size_t)M * H / 8);
  quant_kernel<<<2048, 256, 0, stream>>>(w1, w1q, scal + 1, (size_t)F * H / 8);
  quant_kernel<<<2048, 256, 0, stream>>>(v1, v1q, scal + 2, (size_t)F * H / 8);
  quantT_kernel<<<(F / 64) * (H / 64), 256, 0, stream>>>(w2, w2qT, scal + 3, F, H);

  gemm1_gateup<<<(M / 128) * (F / 128), 256, 0, stream>>>(xq, w1q, v1q, scal, inter,
                                                          scal + 4, M, F, H);
  quant_bf16_kernel<<<2048, 256, 0, stream>>>(inter, midq, scal + 4, (size_t)M * F / 8);
  gemm2_down<<<(M / 128) * (H / 128), 256, 0, stream>>>(midq, w2qT, scal + 4, scal + 3,
                                                        (float*)d_out, M, H, F);
}

// Round 14
// 1004.015 us; speedup vs baseline: 1.3030x; 1.0363x over previous
//
#include <hip/hip_runtime.h>
#include <cstdint>
#include <cstddef>

typedef float f32x4 __attribute__((ext_vector_type(4)));
typedef float f32x16 __attribute__((ext_vector_type(16)));
typedef int i32x4 __attribute__((ext_vector_type(4)));
typedef int i32x8 __attribute__((ext_vector_type(8)));
typedef unsigned char u8;
typedef unsigned short u16;
typedef u16 u16x8 __attribute__((ext_vector_type(8)));

// ---------------- async global->LDS (16B per lane, linear dest) ----------------
static __device__ __forceinline__ void gload_lds16(const void* g, void* l) {
  __builtin_amdgcn_global_load_lds(
      (__attribute__((address_space(1))) void*)(void*)g,
      (__attribute__((address_space(3))) void*)l,
      16, 0, 0);
}

// ---------------- fp8 e4m3fn (OCP) conversion, RNE ----------------
#if defined(__has_builtin)
#if __has_builtin(__builtin_amdgcn_cvt_pk_fp8_f32)
#define HAVE_HW_FP8 1
#endif
#endif

__device__ __forceinline__ u8 f32_to_e4m3_sw(float x) {
  unsigned s = (__float_as_uint(x) >> 24) & 0x80;
  float ax = fabsf(x);
  if (!(ax > 0.0f)) return (u8)s;
  if (ax >= 448.0f) return (u8)(s | 0x7e);
  if (ax < 0.015625f) {            // subnormal, step 2^-9
    int m = (int)rintf(ax * 512.0f);
    if (m >= 8) return (u8)(s | 0x08);
    return (u8)(s | m);
  }
  int e = ilogbf(ax);
  int m = (int)rintf(ldexpf(ax, 3 - e));
  if (m == 16) { ++e; m = 8; }
  return (u8)(s | ((e + 7) << 3) | (m - 8));
}

__device__ __forceinline__ unsigned cvt4_fp8(float a, float b, float c, float d) {
#ifdef HAVE_HW_FP8
  int lo = __builtin_amdgcn_cvt_pk_fp8_f32(a, b, 0, false);
  return (unsigned)__builtin_amdgcn_cvt_pk_fp8_f32(c, d, lo, true);
#else
  return (unsigned)f32_to_e4m3_sw(a) | ((unsigned)f32_to_e4m3_sw(b) << 8) |
         ((unsigned)f32_to_e4m3_sw(c) << 16) | ((unsigned)f32_to_e4m3_sw(d) << 24);
#endif
}

__device__ __forceinline__ u16 f32_to_bf16(float x) {  // RNE
  unsigned u = __float_as_uint(x);
  return (u16)((u + 0x7FFFu + ((u >> 16) & 1u)) >> 16);
}

// ---------------- amax reduction (abs-max via unsigned-bits atomicMax) ----------------
__global__ __launch_bounds__(256) void amax_kernel(const float* __restrict__ src, size_t n4,
                                                   unsigned* __restrict__ out) {
  float m = 0.0f;
  size_t stride = (size_t)gridDim.x * blockDim.x;
  const f32x4* p = (const f32x4*)src;
  for (size_t i = (size_t)blockIdx.x * blockDim.x + threadIdx.x; i < n4; i += stride) {
    f32x4 v = p[i];
    m = fmaxf(m, fmaxf(fmaxf(fabsf(v[0]), fabsf(v[1])), fmaxf(fabsf(v[2]), fabsf(v[3]))));
  }
#pragma unroll
  for (int off = 32; off > 0; off >>= 1) m = fmaxf(m, __shfl_down(m, off));
  __shared__ float red[4];
  int lane = threadIdx.x & 63, wid = threadIdx.x >> 6;
  if (lane == 0) red[wid] = m;
  __syncthreads();
  if (threadIdx.x == 0) {
    float v = fmaxf(fmaxf(red[0], red[1]), fmaxf(red[2], red[3]));
    atomicMax(out, __float_as_uint(v));
  }
}

// ---------------- elementwise quantize f32 -> fp8 (8 elems/thread) ----------------
__global__ __launch_bounds__(256) void quant_kernel(const float* __restrict__ src,
                                                    u8* __restrict__ dst,
                                                    const unsigned* __restrict__ amax_bits,
                                                    size_t n8) {
  float amax = __uint_as_float(*amax_bits);
  float scale = 448.0f / fmaxf(amax, 1e-12f);
  size_t stride = (size_t)gridDim.x * blockDim.x;
  const f32x4* p = (const f32x4*)src;
  uint2* q = (uint2*)dst;
  for (size_t i = (size_t)blockIdx.x * blockDim.x + threadIdx.x; i < n8; i += stride) {
    f32x4 a = p[2 * i], b = p[2 * i + 1];
    float a0 = fminf(fmaxf(a[0] * scale, -448.f), 448.f);
    float a1 = fminf(fmaxf(a[1] * scale, -448.f), 448.f);
    float a2 = fminf(fmaxf(a[2] * scale, -448.f), 448.f);
    float a3 = fminf(fmaxf(a[3] * scale, -448.f), 448.f);
    float b0 = fminf(fmaxf(b[0] * scale, -448.f), 448.f);
    float b1 = fminf(fmaxf(b[1] * scale, -448.f), 448.f);
    float b2 = fminf(fmaxf(b[2] * scale, -448.f), 448.f);
    float b3 = fminf(fmaxf(b[3] * scale, -448.f), 448.f);
    uint2 r;
    r.x = cvt4_fp8(a0, a1, a2, a3);
    r.y = cvt4_fp8(b0, b1, b2, b3);
    q[i] = r;
  }
}

// ---------------- elementwise quantize bf16 -> fp8 (8 elems/thread) ----------------
__global__ __launch_bounds__(256) void quant_bf16_kernel(const u16* __restrict__ src,
                                                         u8* __restrict__ dst,
                                                         const unsigned* __restrict__ amax_bits,
                                                         size_t n8) {
  float amax = __uint_as_float(*amax_bits);
  float scale = 448.0f / fmaxf(amax, 1e-12f);
  size_t stride = (size_t)gridDim.x * blockDim.x;
  const u16x8* p = (const u16x8*)src;
  uint2* q = (uint2*)dst;
  for (size_t i = (size_t)blockIdx.x * blockDim.x + threadIdx.x; i < n8; i += stride) {
    u16x8 v = p[i];
    float f0 = __uint_as_float((unsigned)v[0] << 16) * scale;
    float f1 = __uint_as_float((unsigned)v[1] << 16) * scale;
    float f2 = __uint_as_float((unsigned)v[2] << 16) * scale;
    float f3 = __uint_as_float((unsigned)v[3] << 16) * scale;
    float f4 = __uint_as_float((unsigned)v[4] << 16) * scale;
    float f5 = __uint_as_float((unsigned)v[5] << 16) * scale;
    float f6 = __uint_as_float((unsigned)v[6] << 16) * scale;
    float f7 = __uint_as_float((unsigned)v[7] << 16) * scale;
    f0 = fminf(fmaxf(f0, -448.f), 448.f);
    f1 = fminf(fmaxf(f1, -448.f), 448.f);
    f2 = fminf(fmaxf(f2, -448.f), 448.f);
    f3 = fminf(fmaxf(f3, -448.f), 448.f);
    f4 = fminf(fmaxf(f4, -448.f), 448.f);
    f5 = fminf(fmaxf(f5, -448.f), 448.f);
    f6 = fminf(fmaxf(f6, -448.f), 448.f);
    f7 = fminf(fmaxf(f7, -448.f), 448.f);
    uint2 r;
    r.x = cvt4_fp8(f0, f1, f2, f3);
    r.y = cvt4_fp8(f4, f5, f6, f7);
    q[i] = r;
  }
}

// ---------------- transpose + quantize: src [R][C] f32 -> dst [C][R] fp8 ----------------
__global__ __launch_bounds__(256) void quantT_kernel(const float* __restrict__ src,
                                                     u8* __restrict__ dst,
                                                     const unsigned* __restrict__ amax_bits,
                                                     int R, int C) {
  __shared__ float t[64][65];
  float amax = __uint_as_float(*amax_bits);
  float scale = 448.0f / fmaxf(amax, 1e-12f);
  int nbr = R >> 6;
  int br = (int)blockIdx.x % nbr, bc = (int)blockIdx.x / nbr;
  int r0 = br * 64, c0 = bc * 64;
  int tid = threadIdx.x;
  int lc = tid & 63, lr = tid >> 6;
#pragma unroll
  for (int i = 0; i < 16; ++i)
    t[lr + i * 4][lc] = src[(size_t)(r0 + lr + i * 4) * C + c0 + lc];
  __syncthreads();
  int qd = tid & 15, xbase = tid >> 4;
#pragma unroll
  for (int i = 0; i < 4; ++i) {
    int x = xbase + 16 * i;  // output row index (column of src tile)
    float v0 = fminf(fmaxf(t[4 * qd + 0][x] * scale, -448.f), 448.f);
    float v1 = fminf(fmaxf(t[4 * qd + 1][x] * scale, -448.f), 448.f);
    float v2 = fminf(fmaxf(t[4 * qd + 2][x] * scale, -448.f), 448.f);
    float v3 = fminf(fmaxf(t[4 * qd + 3][x] * scale, -448.f), 448.f);
    *(unsigned*)(dst + (size_t)(c0 + x) * R + r0 + 4 * qd) = cvt4_fp8(v0, v1, v2, v3);
  }
}

// ---------------- LDS address swizzle ----------------
// 16B-block XOR within 64B row, key = (row>>2)&3 (verified conflict-free
// rounds 3/5/6/8/11/13: SQ_LDS_BANK_CONFLICT == 0).
__device__ __forceinline__ int swz_key(int r) { return (r >> 2) & 3; }

__device__ __forceinline__ int swz_off32(int r, int h) {
  return r * 64 + ((((h << 1) ^ swz_key(r)) << 4));
}

// Load a 32B MX-fp8 fragment (k-half h of row r) from a swizzled [*][64] tile.
__device__ __forceinline__ i32x8 ld_frag(const u8* base, int r, int h) {
  int o = swz_off32(r, h);
  i32x8 f;
  f.lo = *(const i32x4*)(base + o);
  f.hi = *(const i32x4*)(base + (o ^ 16));
  return f;
}

#define MFMA_MX(a, b, c) \
  __builtin_amdgcn_mfma_scale_f32_32x32x64_f8f6f4((a), (b), (c), 0, 0, 0, 0x7F7F7F7F, 0, 0x7F7F7F7F)

// ---------------- GEMM1: gate/up fused, NT, MX-fp8, 128x128, 4 waves ----------------
// r13 structure EXACTLY except block ordering: bn-MAJOR linear, NO xcd swizzle.
//   bm = bid & 31, bn = bid >> 5  (M/128 == 32)
// Rationale (r13 counters: FETCH 1.41 GB vs 102 MB L3-resident working set):
// consecutive bids (same bn, all bm) round-robin across the 8 XCDs, so the
// whole chip sweeps ONE 1-MB W/V slice at a time (L2-shared, L3-trivial),
// and XCD = bid mod 8 => bm == XCD (mod 8) stable for the whole kernel =>
// each XCD's 4 A-panels (2 MB) stay L2-resident end-to-end. m160: no-swizzle
// wins when the working set is L3-fit.
__global__ __launch_bounds__(256, 2) void gemm1_gateup(
    const u8* __restrict__ Aq, const u8* __restrict__ Wq, const u8* __restrict__ Vq,
    const unsigned* __restrict__ scal, u16* __restrict__ inter,
    unsigned* __restrict__ amax_mid, int M, int N, int K) {
  __shared__ __align__(16) u8 lA[3][8192], lW[3][8192], lV[3][8192];
  __shared__ float red[4];
  int tid = threadIdx.x;
  int lane = tid & 63, wid = tid >> 6;
  int wm = wid >> 1, wn = wid & 1;  // 2M x 2N waves, per-wave 64x64 dual

  int bid = (int)blockIdx.x;
  int bm = bid & 31;                // M/128 == 32
  int bn = bid >> 5;

  int r0 = tid >> 2;                           // 0..63
  int kblk = ((tid & 3) ^ swz_key(r0)) << 4;   // pre-swizzled global source chunk
  const u8* aS = Aq + (size_t)(bm * 128 + r0) * K + kblk;
  const u8* wS = Wq + (size_t)(bn * 128 + r0) * K + kblk;
  const u8* vS = Vq + (size_t)(bn * 128 + r0) * K + kblk;
  size_t rK = (size_t)64 * K;                  // rows 64..127 (key period 16 -> same kblk)

  f32x16 g00 = (f32x16)(0.f), g01 = (f32x16)(0.f), g10 = (f32x16)(0.f), g11 = (f32x16)(0.f);
  f32x16 u00 = (f32x16)(0.f), u01 = (f32x16)(0.f), u10 = (f32x16)(0.f), u11 = (f32x16)(0.f);

  int rfrag = lane & 31;
  int h = lane >> 5;
  int arow = wm * 64 + rfrag;
  int brow = wn * 64 + rfrag;

  int NT = K >> 6;
  // prologue: stage tiles 0 and 1 (6 loads each)
  {
    gload_lds16(aS + 0, lA[0] + tid * 16);
    gload_lds16(aS + 0 + rK, lA[0] + 4096 + tid * 16);
    gload_lds16(wS + 0, lW[0] + tid * 16);
    gload_lds16(wS + 0 + rK, lW[0] + 4096 + tid * 16);
    gload_lds16(vS + 0, lV[0] + tid * 16);
    gload_lds16(vS + 0 + rK, lV[0] + 4096 + tid * 16);
    gload_lds16(aS + 64, lA[1] + tid * 16);
    gload_lds16(aS + 64 + rK, lA[1] + 4096 + tid * 16);
    gload_lds16(wS + 64, lW[1] + tid * 16);
    gload_lds16(wS + 64 + rK, lW[1] + 4096 + tid * 16);
    gload_lds16(vS + 64, lV[1] + tid * 16);
    gload_lds16(vS + 64 + rK, lV[1] + 4096 + tid * 16);
  }

  for (int t = 0; t < NT; ++t) {
    int cur = t % 3;
    int nx = cur + 2; if (nx >= 3) nx -= 3;   // (t+2)%3
    int kt2 = (t + 2) * 64;
    bool do_stage = (t + 2) < NT;
    // wait: OWN tile-t loads retired; B0 makes it block-wide before any read.
    if (t + 1 < NT) {
      asm volatile("s_waitcnt vmcnt(6)" ::: "memory");
    } else {
      asm volatile("s_waitcnt vmcnt(0)" ::: "memory");
    }
    __builtin_amdgcn_s_barrier();   // B0 (race fix)
    // ---- phase 0: gate ----
    i32x8 a0 = ld_frag(lA[cur], arow, h);
    i32x8 a1 = ld_frag(lA[cur], arow + 32, h);
    i32x8 w0 = ld_frag(lW[cur], brow, h);
    i32x8 w1 = ld_frag(lW[cur], brow + 32, h);
    if (do_stage) {
      gload_lds16(aS + kt2, lA[nx] + tid * 16);
      gload_lds16(aS + kt2 + rK, lA[nx] + 4096 + tid * 16);
      gload_lds16(wS + kt2, lW[nx] + tid * 16);
    }
    __builtin_amdgcn_s_barrier();   // B1
    __builtin_amdgcn_s_setprio(1);
    g00 = MFMA_MX(a0, w0, g00);
    g10 = MFMA_MX(a1, w0, g10);
    g01 = MFMA_MX(a0, w1, g01);
    g11 = MFMA_MX(a1, w1, g11);
    __builtin_amdgcn_s_setprio(0);
    __builtin_amdgcn_s_barrier();   // B2
    // ---- phase 1: up ----
    i32x8 v0 = ld_frag(lV[cur], brow, h);
    i32x8 v1 = ld_frag(lV[cur], brow + 32, h);
    if (do_stage) {
      gload_lds16(wS + kt2 + rK, lW[nx] + 4096 + tid * 16);
      gload_lds16(vS + kt2, lV[nx] + tid * 16);
      gload_lds16(vS + kt2 + rK, lV[nx] + 4096 + tid * 16);
    }
    __builtin_amdgcn_s_barrier();   // B3
    __builtin_amdgcn_s_setprio(1);
    u00 = MFMA_MX(a0, v0, u00);
    u10 = MFMA_MX(a1, v0, u10);
    u01 = MFMA_MX(a0, v1, u01);
    u11 = MFMA_MX(a1, v1, u11);
    __builtin_amdgcn_s_setprio(0);
    // next iteration's B0 doubles as the trailing barrier
  }

  float ax = __uint_as_float(scal[0]);
  float aw = __uint_as_float(scal[1]);
  float av = __uint_as_float(scal[2]);
  float inv_x = 1.0f / (448.0f / fmaxf(ax, 1e-12f));
  float inv_w = 1.0f / (448.0f / fmaxf(aw, 1e-12f));
  float inv_v = 1.0f / (448.0f / fmaxf(av, 1e-12f));
  float sg = inv_x * inv_w, su = inv_x * inv_v;

  // C/D layout 32x32: col = lane&31, row = (reg&3) + 8*(reg>>2) + 4*(lane>>5)
  int rb = bm * 128 + wm * 64 + h * 4;
  int cb = bn * 128 + wn * 64 + rfrag;
  float lmax = 0.0f;
#pragma unroll
  for (int mi = 0; mi < 2; ++mi)
#pragma unroll
    for (int ni = 0; ni < 2; ++ni) {
      const f32x16& gg = mi ? (ni ? g11 : g10) : (ni ? g01 : g00);
      const f32x16& uu = mi ? (ni ? u11 : u10) : (ni ? u01 : u00);
#pragma unroll
      for (int q = 0; q < 16; ++q) {
        int rr = rb + mi * 32 + (q & 3) + 8 * (q >> 2);
        float gv = gg[q] * sg;
        float uv = uu[q] * su;
        float iv = gv / (1.0f + expf(-gv)) * uv;  // silu(g)*u
        inter[(size_t)rr * N + (cb + ni * 32)] = f32_to_bf16(iv);
        lmax = fmaxf(lmax, fabsf(iv));
      }
    }
#pragma unroll
  for (int off = 32; off > 0; off >>= 1) lmax = fmaxf(lmax, __shfl_down(lmax, off));
  if (lane == 0) red[wid] = lmax;
  __syncthreads();
  if (tid == 0)
    atomicMax(amax_mid, __float_as_uint(fmaxf(fmaxf(red[0], red[1]), fmaxf(red[2], red[3]))));
}

// ---------------- GEMM2: down proj, NT vs pre-transposed w2, 128x128 ----------------
// r13 structure exactly; same bn-major no-swizzle ordering (M/128 == 32).
__global__ __launch_bounds__(256, 2) void gemm2_down(
    const u8* __restrict__ Aq, const u8* __restrict__ Bq,
    const unsigned* __restrict__ amax_a, const unsigned* __restrict__ amax_b,
    float* __restrict__ out, int M, int N, int K) {
  __shared__ __align__(16) u8 lA[3][8192], lB[3][8192];
  int tid = threadIdx.x;
  int lane = tid & 63, wid = tid >> 6;
  int wm = wid >> 1, wn = wid & 1;

  int bid = (int)blockIdx.x;
  int bm = bid & 31;                // M/128 == 32
  int bn = bid >> 5;

  int r0 = tid >> 2;
  int kblk = ((tid & 3) ^ swz_key(r0)) << 4;
  const u8* aS = Aq + (size_t)(bm * 128 + r0) * K + kblk;
  const u8* bS = Bq + (size_t)(bn * 128 + r0) * K + kblk;
  size_t rK = (size_t)64 * K;

  f32x16 c00 = (f32x16)(0.f), c01 = (f32x16)(0.f);
  f32x16 c10 = (f32x16)(0.f), c11 = (f32x16)(0.f);

  int rfrag = lane & 31;
  int h = lane >> 5;
  int arow = wm * 64 + rfrag;
  int brow = wn * 64 + rfrag;

  int NT = K >> 6;
  {
    gload_lds16(aS + 0, lA[0] + tid * 16);
    gload_lds16(aS + 0 + rK, lA[0] + 4096 + tid * 16);
    gload_lds16(bS + 0, lB[0] + tid * 16);
    gload_lds16(bS + 0 + rK, lB[0] + 4096 + tid * 16);
    gload_lds16(aS + 64, lA[1] + tid * 16);
    gload_lds16(aS + 64 + rK, lA[1] + 4096 + tid * 16);
    gload_lds16(bS + 64, lB[1] + tid * 16);
    gload_lds16(bS + 64 + rK, lB[1] + 4096 + tid * 16);
  }

  for (int t = 0; t < NT; ++t) {
    int cur = t % 3;
    int nx = cur + 2; if (nx >= 3) nx -= 3;
    int kt2 = (t + 2) * 64;
    bool do_stage = (t + 2) < NT;
    if (t + 1 < NT) {
      asm volatile("s_waitcnt vmcnt(4)" ::: "memory");
    } else {
      asm volatile("s_waitcnt vmcnt(0)" ::: "memory");
    }
    __builtin_amdgcn_s_barrier();   // B0 (race fix)
    // ---- phase 0 ----
    i32x8 a0 = ld_frag(lA[cur], arow, h);
    i32x8 a1 = ld_frag(lA[cur], arow + 32, h);
    i32x8 b0 = ld_frag(lB[cur], brow, h);
    if (do_stage) {
      gload_lds16(aS + kt2, lA[nx] + tid * 16);
      gload_lds16(aS + kt2 + rK, lA[nx] + 4096 + tid * 16);
    }
    __builtin_amdgcn_s_barrier();
    __builtin_amdgcn_s_setprio(1);
    c00 = MFMA_MX(a0, b0, c00);
    c10 = MFMA_MX(a1, b0, c10);
    __builtin_amdgcn_s_setprio(0);
    __builtin_amdgcn_s_barrier();
    // ---- phase 1 ----
    i32x8 b1 = ld_frag(lB[cur], brow + 32, h);
    if (do_stage) {
      gload_lds16(bS + kt2, lB[nx] + tid * 16);
      gload_lds16(bS + kt2 + rK, lB[nx] + 4096 + tid * 16);
    }
    __builtin_amdgcn_s_barrier();
    __builtin_amdgcn_s_setprio(1);
    c01 = MFMA_MX(a0, b1, c01);
    c11 = MFMA_MX(a1, b1, c11);
    __builtin_amdgcn_s_setprio(0);
  }

  float sa = 1.0f / (448.0f / fmaxf(__uint_as_float(*amax_a), 1e-12f));
  float sb = 1.0f / (448.0f / fmaxf(__uint_as_float(*amax_b), 1e-12f));
  float sc = sa * sb;

  int rb = bm * 128 + wm * 64 + h * 4;
  int cb = bn * 128 + wn * 64 + rfrag;
#pragma unroll
  for (int mi = 0; mi < 2; ++mi)
#pragma unroll
    for (int ni = 0; ni < 2; ++ni) {
      const f32x16& cc = mi ? (ni ? c11 : c10) : (ni ? c01 : c00);
#pragma unroll
      for (int q = 0; q < 16; ++q) {
        int rr = rb + mi * 32 + (q & 3) + 8 * (q >> 2);
        out[(size_t)rr * N + (cb + ni * 32)] = cc[q] * sc;
      }
    }
}

// ---------------- host launcher ----------------
extern "C" void kernel_launch(void* const* d_in, const int* in_sizes, int n_in,
                              void* d_out, int out_size, void* d_ws, size_t ws_size,
                              hipStream_t stream) {
  const float* x  = (const float*)d_in[0];
  const float* w1 = (const float*)d_in[1];
  const float* v1 = (const float*)d_in[2];
  const float* w2 = (const float*)d_in[3];
  const int M = 4096, H = 4096, F = 10752;

  u8* ws = (u8*)d_ws;
  unsigned* scal = (unsigned*)ws;          // [0]=x [1]=w1 [2]=v1 [3]=w2 [4]=mid
  u8* xq   = ws + 256;
  u8* w1q  = xq   + (size_t)M * H;
  u8* v1q  = w1q  + (size_t)F * H;
  u8* w2qT = v1q  + (size_t)F * H;
  u8* midq = w2qT + (size_t)F * H;
  u16* inter = (u16*)(midq + (size_t)M * F);   // bf16 inter (halved traffic)

  hipMemsetAsync(scal, 0, 256, stream);
  amax_kernel<<<2048, 256, 0, stream>>>(x,  (size_t)M * H / 4, scal + 0);
  amax_kernel<<<2048, 256, 0, stream>>>(w1, (size_t)F * H / 4, scal + 1);
  amax_kernel<<<2048, 256, 0, stream>>>(v1, (size_t)F * H / 4, scal + 2);
  amax_kernel<<<2048, 256, 0, stream>>>(w2, (size_t)F * H / 4, scal + 3);

  quant_kernel<<<2048, 256, 0, stream>>>(x,  xq,  scal + 0, (size_t)M * H / 8);
  quant_kernel<<<2048, 256, 0, stream>>>(w1, w1q, scal + 1, (size_t)F * H / 8);
  quant_kernel<<<2048, 256, 0, stream>>>(v1, v1q, scal + 2, (size_t)F * H / 8);
  quantT_kernel<<<(F / 64) * (H / 64), 256, 0, stream>>>(w2, w2qT, scal + 3, F, H);

  gemm1_gateup<<<(M / 128) * (F / 128), 256, 0, stream>>>(xq, w1q, v1q, scal, inter,
                                                          scal + 4, M, F, H);
  quant_bf16_kernel<<<2048, 256, 0, stream>>>(inter, midq, scal + 4, (size_t)M * F / 8);
  gemm2_down<<<(M / 128) * (H / 128), 256, 0, stream>>>(midq, w2qT, scal + 4, scal + 3,
                                                        (float*)d_out, M, H, F);
}

// Round 15
// 988.949 us; speedup vs baseline: 1.3229x; 1.0152x over previous
//
#include <hip/hip_runtime.h>
#include <cstdint>
#include <cstddef>

typedef float f32x4 __attribute__((ext_vector_type(4)));
typedef float f32x16 __attribute__((ext_vector_type(16)));
typedef int i32x4 __attribute__((ext_vector_type(4)));
typedef int i32x8 __attribute__((ext_vector_type(8)));
typedef unsigned char u8;
typedef unsigned short u16;
typedef u16 u16x8 __attribute__((ext_vector_type(8)));
typedef unsigned int u32;
typedef u32 u32x4 __attribute__((ext_vector_type(4)));

// ---------------- async global->LDS (16B per lane, linear dest) ----------------
static __device__ __forceinline__ void gload_lds16(const void* g, void* l) {
  __builtin_amdgcn_global_load_lds(
      (__attribute__((address_space(1))) void*)(void*)g,
      (__attribute__((address_space(3))) void*)l,
      16, 0, 0);
}

// ---------------- fp8 e4m3fn (OCP) conversion, RNE ----------------
#if defined(__has_builtin)
#if __has_builtin(__builtin_amdgcn_cvt_pk_fp8_f32)
#define HAVE_HW_FP8 1
#endif
#endif

__device__ __forceinline__ u8 f32_to_e4m3_sw(float x) {
  unsigned s = (__float_as_uint(x) >> 24) & 0x80;
  float ax = fabsf(x);
  if (!(ax > 0.0f)) return (u8)s;
  if (ax >= 448.0f) return (u8)(s | 0x7e);
  if (ax < 0.015625f) {            // subnormal, step 2^-9
    int m = (int)rintf(ax * 512.0f);
    if (m >= 8) return (u8)(s | 0x08);
    return (u8)(s | m);
  }
  int e = ilogbf(ax);
  int m = (int)rintf(ldexpf(ax, 3 - e));
  if (m == 16) { ++e; m = 8; }
  return (u8)(s | ((e + 7) << 3) | (m - 8));
}

__device__ __forceinline__ unsigned cvt4_fp8(float a, float b, float c, float d) {
#ifdef HAVE_HW_FP8
  int lo = __builtin_amdgcn_cvt_pk_fp8_f32(a, b, 0, false);
  return (unsigned)__builtin_amdgcn_cvt_pk_fp8_f32(c, d, lo, true);
#else
  return (unsigned)f32_to_e4m3_sw(a) | ((unsigned)f32_to_e4m3_sw(b) << 8) |
         ((unsigned)f32_to_e4m3_sw(c) << 16) | ((unsigned)f32_to_e4m3_sw(d) << 24);
#endif
}

__device__ __forceinline__ float clamp448(float x) {
  return fminf(fmaxf(x, -448.f), 448.f);
}

__device__ __forceinline__ u16 f32_to_bf16(float x) {  // RNE
  unsigned u = __float_as_uint(x);
  return (u16)((u + 0x7FFFu + ((u >> 16) & 1u)) >> 16);
}

// ---------------- amax reduction (abs-max via unsigned-bits atomicMax) ----------------
__global__ __launch_bounds__(256) void amax_kernel(const float* __restrict__ src, size_t n4,
                                                   unsigned* __restrict__ out) {
  float m = 0.0f;
  size_t stride = (size_t)gridDim.x * blockDim.x;
  const f32x4* p = (const f32x4*)src;
  for (size_t i = (size_t)blockIdx.x * blockDim.x + threadIdx.x; i < n4; i += stride) {
    f32x4 v = p[i];
    m = fmaxf(m, fmaxf(fmaxf(fabsf(v[0]), fabsf(v[1])), fmaxf(fabsf(v[2]), fabsf(v[3]))));
  }
#pragma unroll
  for (int off = 32; off > 0; off >>= 1) m = fmaxf(m, __shfl_down(m, off));
  __shared__ float red[4];
  int lane = threadIdx.x & 63, wid = threadIdx.x >> 6;
  if (lane == 0) red[wid] = m;
  __syncthreads();
  if (threadIdx.x == 0) {
    float v = fmaxf(fmaxf(red[0], red[1]), fmaxf(red[2], red[3]));
    atomicMax(out, __float_as_uint(v));
  }
}

// ---------------- elementwise quantize f32 -> fp8 linear (W/V, B-operands) ----------------
__global__ __launch_bounds__(256) void quant_kernel(const float* __restrict__ src,
                                                    u8* __restrict__ dst,
                                                    const unsigned* __restrict__ amax_bits,
                                                    size_t n8) {
  float amax = __uint_as_float(*amax_bits);
  float scale = 448.0f / fmaxf(amax, 1e-12f);
  size_t stride = (size_t)gridDim.x * blockDim.x;
  const f32x4* p = (const f32x4*)src;
  uint2* q = (uint2*)dst;
  for (size_t i = (size_t)blockIdx.x * blockDim.x + threadIdx.x; i < n8; i += stride) {
    f32x4 a = p[2 * i], b = p[2 * i + 1];
    uint2 r;
    r.x = cvt4_fp8(clamp448(a[0] * scale), clamp448(a[1] * scale),
                   clamp448(a[2] * scale), clamp448(a[3] * scale));
    r.y = cvt4_fp8(clamp448(b[0] * scale), clamp448(b[1] * scale),
                   clamp448(b[2] * scale), clamp448(b[3] * scale));
    q[i] = r;
  }
}

// ---------------- pack-quantize f32 [4096][K] -> fp8 Apk[K/32][4096][32] ----------------
// chunk c: m = c & 4095, kb = c >> 12. Reads 128B contiguous per thread
// (= exactly 2 cache lines, no waste); writes: consecutive threads (same kb,
// consecutive m) -> contiguous 32B chunks = fully coalesced.
__global__ __launch_bounds__(256) void pack_f32_kernel(const float* __restrict__ src,
                                                       u8* __restrict__ dst,
                                                       const unsigned* __restrict__ amax_bits,
                                                       int K) {
  float amax = __uint_as_float(*amax_bits);
  float scale = 448.0f / fmaxf(amax, 1e-12f);
  int c = (int)blockIdx.x * 256 + (int)threadIdx.x;
  int m = c & 4095;
  int kb = c >> 12;
  const f32x4* s = (const f32x4*)(src + (size_t)m * K + kb * 32);
  unsigned w[8];
#pragma unroll
  for (int j = 0; j < 8; ++j) {
    f32x4 v = s[j];
    w[j] = cvt4_fp8(clamp448(v[0] * scale), clamp448(v[1] * scale),
                    clamp448(v[2] * scale), clamp448(v[3] * scale));
  }
  u32x4* d = (u32x4*)(dst + ((size_t)kb * 4096 + m) * 32);
  d[0] = u32x4{w[0], w[1], w[2], w[3]};
  d[1] = u32x4{w[4], w[5], w[6], w[7]};
}

// ---------------- pack-quantize bf16 [4096][K] -> fp8 Apk[K/32][4096][32] ----------------
__global__ __launch_bounds__(256) void pack_bf16_kernel(const u16* __restrict__ src,
                                                        u8* __restrict__ dst,
                                                        const unsigned* __restrict__ amax_bits,
                                                        int K) {
  float amax = __uint_as_float(*amax_bits);
  float scale = 448.0f / fmaxf(amax, 1e-12f);
  int c = (int)blockIdx.x * 256 + (int)threadIdx.x;
  int m = c & 4095;
  int kb = c >> 12;
  const u16x8* s = (const u16x8*)(src + (size_t)m * K + kb * 32);
  unsigned w[8];
#pragma unroll
  for (int j = 0; j < 4; ++j) {
    u16x8 v = s[j];
    float f0 = __uint_as_float((unsigned)v[0] << 16) * scale;
    float f1 = __uint_as_float((unsigned)v[1] << 16) * scale;
    float f2 = __uint_as_float((unsigned)v[2] << 16) * scale;
    float f3 = __uint_as_float((unsigned)v[3] << 16) * scale;
    float f4 = __uint_as_float((unsigned)v[4] << 16) * scale;
    float f5 = __uint_as_float((unsigned)v[5] << 16) * scale;
    float f6 = __uint_as_float((unsigned)v[6] << 16) * scale;
    float f7 = __uint_as_float((unsigned)v[7] << 16) * scale;
    w[2 * j]     = cvt4_fp8(clamp448(f0), clamp448(f1), clamp448(f2), clamp448(f3));
    w[2 * j + 1] = cvt4_fp8(clamp448(f4), clamp448(f5), clamp448(f6), clamp448(f7));
  }
  u32x4* d = (u32x4*)(dst + ((size_t)kb * 4096 + m) * 32);
  d[0] = u32x4{w[0], w[1], w[2], w[3]};
  d[1] = u32x4{w[4], w[5], w[6], w[7]};
}

// ---------------- transpose + quantize: src [R][C] f32 -> dst [C][R] fp8 ----------------
__global__ __launch_bounds__(256) void quantT_kernel(const float* __restrict__ src,
                                                     u8* __restrict__ dst,
                                                     const unsigned* __restrict__ amax_bits,
                                                     int R, int C) {
  __shared__ float t[64][65];
  float amax = __uint_as_float(*amax_bits);
  float scale = 448.0f / fmaxf(amax, 1e-12f);
  int nbr = R >> 6;
  int br = (int)blockIdx.x % nbr, bc = (int)blockIdx.x / nbr;
  int r0 = br * 64, c0 = bc * 64;
  int tid = threadIdx.x;
  int lc = tid & 63, lr = tid >> 6;
#pragma unroll
  for (int i = 0; i < 16; ++i)
    t[lr + i * 4][lc] = src[(size_t)(r0 + lr + i * 4) * C + c0 + lc];
  __syncthreads();
  int qd = tid & 15, xbase = tid >> 4;
#pragma unroll
  for (int i = 0; i < 4; ++i) {
    int x = xbase + 16 * i;  // output row index (column of src tile)
    float v0 = clamp448(t[4 * qd + 0][x] * scale);
    float v1 = clamp448(t[4 * qd + 1][x] * scale);
    float v2 = clamp448(t[4 * qd + 2][x] * scale);
    float v3 = clamp448(t[4 * qd + 3][x] * scale);
    *(unsigned*)(dst + (size_t)(c0 + x) * R + r0 + 4 * qd) = cvt4_fp8(v0, v1, v2, v3);
  }
}

// ---------------- LDS address swizzle ----------------
// 16B-block XOR within 64B row, key = (row>>2)&3 (verified conflict-free
// rounds 3/5/6/8/11/13/14: SQ_LDS_BANK_CONFLICT == 0).
__device__ __forceinline__ int swz_key(int r) { return (r >> 2) & 3; }

__device__ __forceinline__ int swz_off32(int r, int h) {
  return r * 64 + ((((h << 1) ^ swz_key(r)) << 4));
}

// Load a 32B MX-fp8 fragment (k-half h of row r) from a swizzled [*][64] tile.
__device__ __forceinline__ i32x8 ld_frag(const u8* base, int r, int h) {
  int o = swz_off32(r, h);
  i32x8 f;
  f.lo = *(const i32x4*)(base + o);
  f.hi = *(const i32x4*)(base + (o ^ 16));
  return f;
}

// Load a 32B packed-A fragment straight from global (coalesced: lanes with
// same h read consecutive 32B chunks -> one 1KB segment per 32-lane group).
__device__ __forceinline__ i32x8 ld_a_g(const u8* p) {
  i32x8 f;
  f.lo = *(const i32x4*)p;
  f.hi = *(const i32x4*)(p + 16);
  return f;
}

#define MFMA_MX(a, b, c) \
  __builtin_amdgcn_mfma_scale_f32_32x32x64_f8f6f4((a), (b), (c), 0, 0, 0, 0x7F7F7F7F, 0, 0x7F7F7F7F)

// ---------------- GEMM1: gate/up fused, NT, MX-fp8, 128x128, 4 waves ----------------
// r14 structure + PACKED-A-from-global: A bypasses LDS entirely (the r12 idea,
// fixed: Apk layout makes the per-lane fragment loads coalesced). LDS traffic
// per block-K-step 72->48 KB; LDS 74->48 KB -> 3 blocks/CU.
// vmcnt derivation (robust to intra-iter reorder): loads needed at B0 of iter
// t (stW(t),stV(t), issued iter t-2) are strictly OLDER than everything else
// outstanding; younger = exactly one iter's VMEM issue = aPref(4)+stages(4)=8
// -> vmcnt(8). B0 barrier after the wait makes visibility block-wide (r9).
__global__ __launch_bounds__(256, 2) void gemm1_gateup(
    const u8* __restrict__ Apk, const u8* __restrict__ Wq, const u8* __restrict__ Vq,
    const unsigned* __restrict__ scal, u16* __restrict__ inter,
    unsigned* __restrict__ amax_mid, int M, int N, int K) {
  __shared__ __align__(16) u8 lW[3][8192], lV[3][8192];
  __shared__ float red[4];
  int tid = threadIdx.x;
  int lane = tid & 63, wid = tid >> 6;
  int wm = wid >> 1, wn = wid & 1;  // 2M x 2N waves, per-wave 64x64 dual

  int bid = (int)blockIdx.x;
  int bm = bid & 31;                // M/128 == 32; bn-major (r14: L2/L3 residency)
  int bn = bid >> 5;

  int r0 = tid >> 2;                           // 0..63
  int kblk = ((tid & 3) ^ swz_key(r0)) << 4;   // pre-swizzled global source chunk
  const u8* wS = Wq + (size_t)(bn * 128 + r0) * K + kblk;
  const u8* vS = Vq + (size_t)(bn * 128 + r0) * K + kblk;
  size_t rK = (size_t)64 * K;                  // rows 64..127 (key period 16 -> same kblk)

  f32x16 g00 = (f32x16)(0.f), g01 = (f32x16)(0.f), g10 = (f32x16)(0.f), g11 = (f32x16)(0.f);
  f32x16 u00 = (f32x16)(0.f), u01 = (f32x16)(0.f), u10 = (f32x16)(0.f), u11 = (f32x16)(0.f);

  int rfrag = lane & 31;
  int h = lane >> 5;
  int arow = wm * 64 + rfrag;
  int brow = wn * 64 + rfrag;

  // packed-A: addr(t,h,r) = ((2t+h)*M + r)*32
  const size_t tStride = (size_t)64 * M;
  const u8* aP = Apk + 32 * ((size_t)M * h + (size_t)(bm * 128 + arow));

  int NT = K >> 6;
  // prologue: stage W/V tiles 0,1 (4 loads each); then A-frags for tile 0
  {
    gload_lds16(wS + 0, lW[0] + tid * 16);
    gload_lds16(wS + 0 + rK, lW[0] + 4096 + tid * 16);
    gload_lds16(vS + 0, lV[0] + tid * 16);
    gload_lds16(vS + 0 + rK, lV[0] + 4096 + tid * 16);
    gload_lds16(wS + 64, lW[1] + tid * 16);
    gload_lds16(wS + 64 + rK, lW[1] + 4096 + tid * 16);
    gload_lds16(vS + 64, lV[1] + tid * 16);
    gload_lds16(vS + 64 + rK, lV[1] + 4096 + tid * 16);
  }
  i32x8 ac0 = ld_a_g(aP);
  i32x8 ac1 = ld_a_g(aP + 1024);
  i32x8 an0 = ac0, an1 = ac1;

  for (int t = 0; t < NT; ++t) {
    int cur = t % 3;
    int nx = cur + 2; if (nx >= 3) nx -= 3;   // (t+2)%3
    int kt2 = (t + 2) * 64;
    bool do_stage = (t + 2) < NT;
    bool do_pref = (t + 1) < NT;
    if (do_pref) {
      asm volatile("s_waitcnt vmcnt(8)" ::: "memory");
    } else {
      asm volatile("s_waitcnt vmcnt(0)" ::: "memory");
    }
    __builtin_amdgcn_s_barrier();   // B0 (race fix)
    // ---- phase 0: gate ----
    i32x8 w0 = ld_frag(lW[cur], brow, h);
    i32x8 w1 = ld_frag(lW[cur], brow + 32, h);
    if (do_pref) {                  // packed-A prefetch for t+1 (own-wave regs)
      const u8* ap = aP + (size_t)(t + 1) * tStride;
      an0 = ld_a_g(ap);
      an1 = ld_a_g(ap + 1024);
    }
    if (do_stage) {
      gload_lds16(wS + kt2, lW[nx] + tid * 16);
      gload_lds16(wS + kt2 + rK, lW[nx] + 4096 + tid * 16);
    }
    __builtin_amdgcn_s_barrier();   // B1
    __builtin_amdgcn_s_setprio(1);
    g00 = MFMA_MX(ac0, w0, g00);
    g10 = MFMA_MX(ac1, w0, g10);
    g01 = MFMA_MX(ac0, w1, g01);
    g11 = MFMA_MX(ac1, w1, g11);
    __builtin_amdgcn_s_setprio(0);
    __builtin_amdgcn_s_barrier();   // B2
    // ---- phase 1: up ----
    i32x8 v0 = ld_frag(lV[cur], brow, h);
    i32x8 v1 = ld_frag(lV[cur], brow + 32, h);
    if (do_stage) {
      gload_lds16(vS + kt2, lV[nx] + tid * 16);
      gload_lds16(vS + kt2 + rK, lV[nx] + 4096 + tid * 16);
    }
    __builtin_amdgcn_s_barrier();   // B3
    __builtin_amdgcn_s_setprio(1);
    u00 = MFMA_MX(ac0, v0, u00);
    u10 = MFMA_MX(ac1, v0, u10);
    u01 = MFMA_MX(ac0, v1, u01);
    u11 = MFMA_MX(ac1, v1, u11);
    __builtin_amdgcn_s_setprio(0);
    ac0 = an0; ac1 = an1;           // advance A pipeline
    // next iteration's B0 doubles as the trailing barrier
  }

  float ax = __uint_as_float(scal[0]);
  float aw = __uint_as_float(scal[1]);
  float av = __uint_as_float(scal[2]);
  float inv_x = 1.0f / (448.0f / fmaxf(ax, 1e-12f));
  float inv_w = 1.0f / (448.0f / fmaxf(aw, 1e-12f));
  float inv_v = 1.0f / (448.0f / fmaxf(av, 1e-12f));
  float sg = inv_x * inv_w, su = inv_x * inv_v;

  // C/D layout 32x32: col = lane&31, row = (reg&3) + 8*(reg>>2) + 4*(lane>>5)
  int rb = bm * 128 + wm * 64 + h * 4;
  int cb = bn * 128 + wn * 64 + rfrag;
  float lmax = 0.0f;
#pragma unroll
  for (int mi = 0; mi < 2; ++mi)
#pragma unroll
    for (int ni = 0; ni < 2; ++ni) {
      const f32x16& gg = mi ? (ni ? g11 : g10) : (ni ? g01 : g00);
      const f32x16& uu = mi ? (ni ? u11 : u10) : (ni ? u01 : u00);
#pragma unroll
      for (int q = 0; q < 16; ++q) {
        int rr = rb + mi * 32 + (q & 3) + 8 * (q >> 2);
        float gv = gg[q] * sg;
        float uv = uu[q] * su;
        float iv = gv / (1.0f + expf(-gv)) * uv;  // silu(g)*u
        inter[(size_t)rr * N + (cb + ni * 32)] = f32_to_bf16(iv);
        lmax = fmaxf(lmax, fabsf(iv));
      }
    }
#pragma unroll
  for (int off = 32; off > 0; off >>= 1) lmax = fmaxf(lmax, __shfl_down(lmax, off));
  if (lane == 0) red[wid] = lmax;
  __syncthreads();
  if (tid == 0)
    atomicMax(amax_mid, __float_as_uint(fmaxf(fmaxf(red[0], red[1]), fmaxf(red[2], red[3]))));
}

// ---------------- GEMM2: down proj, NT vs pre-transposed w2, 128x128 ----------------
// Packed-A (midq) from global; B via LDS tri-buffer. Per-iter VMEM =
// aPref(4)+stB(2) = 6 -> vmcnt(6). LDS 24 KB.
__global__ __launch_bounds__(256, 2) void gemm2_down(
    const u8* __restrict__ Apk, const u8* __restrict__ Bq,
    const unsigned* __restrict__ amax_a, const unsigned* __restrict__ amax_b,
    float* __restrict__ out, int M, int N, int K) {
  __shared__ __align__(16) u8 lB[3][8192];
  int tid = threadIdx.x;
  int lane = tid & 63, wid = tid >> 6;
  int wm = wid >> 1, wn = wid & 1;

  int bid = (int)blockIdx.x;
  int bm = bid & 31;                // M/128 == 32; bn-major
  int bn = bid >> 5;

  int r0 = tid >> 2;
  int kblk = ((tid & 3) ^ swz_key(r0)) << 4;
  const u8* bS = Bq + (size_t)(bn * 128 + r0) * K + kblk;
  size_t rK = (size_t)64 * K;

  f32x16 c00 = (f32x16)(0.f), c01 = (f32x16)(0.f);
  f32x16 c10 = (f32x16)(0.f), c11 = (f32x16)(0.f);

  int rfrag = lane & 31;
  int h = lane >> 5;
  int arow = wm * 64 + rfrag;
  int brow = wn * 64 + rfrag;

  const size_t tStride = (size_t)64 * M;
  const u8* aP = Apk + 32 * ((size_t)M * h + (size_t)(bm * 128 + arow));

  int NT = K >> 6;
  {
    gload_lds16(bS + 0, lB[0] + tid * 16);
    gload_lds16(bS + 0 + rK, lB[0] + 4096 + tid * 16);
    gload_lds16(bS + 64, lB[1] + tid * 16);
    gload_lds16(bS + 64 + rK, lB[1] + 4096 + tid * 16);
  }
  i32x8 ac0 = ld_a_g(aP);
  i32x8 ac1 = ld_a_g(aP + 1024);
  i32x8 an0 = ac0, an1 = ac1;

  for (int t = 0; t < NT; ++t) {
    int cur = t % 3;
    int nx = cur + 2; if (nx >= 3) nx -= 3;
    int kt2 = (t + 2) * 64;
    bool do_stage = (t + 2) < NT;
    bool do_pref = (t + 1) < NT;
    if (do_pref) {
      asm volatile("s_waitcnt vmcnt(6)" ::: "memory");
    } else {
      asm volatile("s_waitcnt vmcnt(0)" ::: "memory");
    }
    __builtin_amdgcn_s_barrier();   // B0 (race fix)
    // ---- phase 0 ----
    i32x8 b0 = ld_frag(lB[cur], brow, h);
    if (do_pref) {
      const u8* ap = aP + (size_t)(t + 1) * tStride;
      an0 = ld_a_g(ap);
      an1 = ld_a_g(ap + 1024);
    }
    if (do_stage) {
      gload_lds16(bS + kt2, lB[nx] + tid * 16);
      gload_lds16(bS + kt2 + rK, lB[nx] + 4096 + tid * 16);
    }
    __builtin_amdgcn_s_barrier();
    __builtin_amdgcn_s_setprio(1);
    c00 = MFMA_MX(ac0, b0, c00);
    c10 = MFMA_MX(ac1, b0, c10);
    __builtin_amdgcn_s_setprio(0);
    __builtin_amdgcn_s_barrier();
    // ---- phase 1 ----
    i32x8 b1 = ld_frag(lB[cur], brow + 32, h);
    __builtin_amdgcn_s_barrier();
    __builtin_amdgcn_s_setprio(1);
    c01 = MFMA_MX(ac0, b1, c01);
    c11 = MFMA_MX(ac1, b1, c11);
    __builtin_amdgcn_s_setprio(0);
    ac0 = an0; ac1 = an1;
  }

  float sa = 1.0f / (448.0f / fmaxf(__uint_as_float(*amax_a), 1e-12f));
  float sb = 1.0f / (448.0f / fmaxf(__uint_as_float(*amax_b), 1e-12f));
  float sc = sa * sb;

  int rb = bm * 128 + wm * 64 + h * 4;
  int cb = bn * 128 + wn * 64 + rfrag;
#pragma unroll
  for (int mi = 0; mi < 2; ++mi)
#pragma unroll
    for (int ni = 0; ni < 2; ++ni) {
      const f32x16& cc = mi ? (ni ? c11 : c10) : (ni ? c01 : c00);
#pragma unroll
      for (int q = 0; q < 16; ++q) {
        int rr = rb + mi * 32 + (q & 3) + 8 * (q >> 2);
        out[(size_t)rr * N + (cb + ni * 32)] = cc[q] * sc;
      }
    }
}

// ---------------- host launcher ----------------
extern "C" void kernel_launch(void* const* d_in, const int* in_sizes, int n_in,
                              void* d_out, int out_size, void* d_ws, size_t ws_size,
                              hipStream_t stream) {
  const float* x  = (const float*)d_in[0];
  const float* w1 = (const float*)d_in[1];
  const float* v1 = (const float*)d_in[2];
  const float* w2 = (const float*)d_in[3];
  const int M = 4096, H = 4096, F = 10752;

  u8* ws = (u8*)d_ws;
  unsigned* scal = (unsigned*)ws;          // [0]=x [1]=w1 [2]=v1 [3]=w2 [4]=mid
  u8* xpk  = ws + 256;                     // packed A for gemm1 [H/32][M][32]
  u8* w1q  = xpk  + (size_t)M * H;
  u8* v1q  = w1q  + (size_t)F * H;
  u8* w2qT = v1q  + (size_t)F * H;
  u8* midpk = w2qT + (size_t)F * H;        // packed A for gemm2 [F/32][M][32]
  u16* inter = (u16*)(midpk + (size_t)M * F);  // bf16 inter

  hipMemsetAsync(scal, 0, 256, stream);
  amax_kernel<<<2048, 256, 0, stream>>>(x,  (size_t)M * H / 4, scal + 0);
  amax_kernel<<<2048, 256, 0, stream>>>(w1, (size_t)F * H / 4, scal + 1);
  amax_kernel<<<2048, 256, 0, stream>>>(v1, (size_t)F * H / 4, scal + 2);
  amax_kernel<<<2048, 256, 0, stream>>>(w2, (size_t)F * H / 4, scal + 3);

  pack_f32_kernel<<<(M * (H / 32)) / 256, 256, 0, stream>>>(x, xpk, scal + 0, H);
  quant_kernel<<<2048, 256, 0, stream>>>(w1, w1q, scal + 1, (size_t)F * H / 8);
  quant_kernel<<<2048, 256, 0, stream>>>(v1, v1q, scal + 2, (size_t)F * H / 8);
  quantT_kernel<<<(F / 64) * (H / 64), 256, 0, stream>>>(w2, w2qT, scal + 3, F, H);

  gemm1_gateup<<<(M / 128) * (F / 128), 256, 0, stream>>>(xpk, w1q, v1q, scal, inter,
                                                          scal + 4, M, F, H);
  pack_bf16_kernel<<<(M * (F / 32)) / 256, 256, 0, stream>>>(inter, midpk, scal + 4, F);
  gemm2_down<<<(M / 128) * (H / 128), 256, 0, stream>>>(midpk, w2qT, scal + 4, scal + 3,
                                                        (float*)d_out, M, H, F);
}

// Round 16
// 975.446 us; speedup vs baseline: 1.3412x; 1.0138x over previous
//
#include <hip/hip_runtime.h>
#include <cstdint>
#include <cstddef>

typedef float f32x4 __attribute__((ext_vector_type(4)));
typedef float f32x16 __attribute__((ext_vector_type(16)));
typedef int i32x4 __attribute__((ext_vector_type(4)));
typedef int i32x8 __attribute__((ext_vector_type(8)));
typedef unsigned char u8;
typedef unsigned short u16;
typedef u16 u16x8 __attribute__((ext_vector_type(8)));
typedef unsigned int u32;
typedef u32 u32x4 __attribute__((ext_vector_type(4)));

// ---------------- async global->LDS (16B per lane, linear dest) ----------------
static __device__ __forceinline__ void gload_lds16(const void* g, void* l) {
  __builtin_amdgcn_global_load_lds(
      (__attribute__((address_space(1))) void*)(void*)g,
      (__attribute__((address_space(3))) void*)l,
      16, 0, 0);
}

// ---------------- fp8 e4m3fn (OCP) conversion, RNE ----------------
#if defined(__has_builtin)
#if __has_builtin(__builtin_amdgcn_cvt_pk_fp8_f32)
#define HAVE_HW_FP8 1
#endif
#endif

__device__ __forceinline__ u8 f32_to_e4m3_sw(float x) {
  unsigned s = (__float_as_uint(x) >> 24) & 0x80;
  float ax = fabsf(x);
  if (!(ax > 0.0f)) return (u8)s;
  if (ax >= 448.0f) return (u8)(s | 0x7e);
  if (ax < 0.015625f) {            // subnormal, step 2^-9
    int m = (int)rintf(ax * 512.0f);
    if (m >= 8) return (u8)(s | 0x08);
    return (u8)(s | m);
  }
  int e = ilogbf(ax);
  int m = (int)rintf(ldexpf(ax, 3 - e));
  if (m == 16) { ++e; m = 8; }
  return (u8)(s | ((e + 7) << 3) | (m - 8));
}

__device__ __forceinline__ unsigned cvt4_fp8(float a, float b, float c, float d) {
#ifdef HAVE_HW_FP8
  int lo = __builtin_amdgcn_cvt_pk_fp8_f32(a, b, 0, false);
  return (unsigned)__builtin_amdgcn_cvt_pk_fp8_f32(c, d, lo, true);
#else
  return (unsigned)f32_to_e4m3_sw(a) | ((unsigned)f32_to_e4m3_sw(b) << 8) |
         ((unsigned)f32_to_e4m3_sw(c) << 16) | ((unsigned)f32_to_e4m3_sw(d) << 24);
#endif
}

__device__ __forceinline__ float clamp448(float x) {
  return fminf(fmaxf(x, -448.f), 448.f);
}

__device__ __forceinline__ u16 f32_to_bf16(float x) {  // RNE
  unsigned u = __float_as_uint(x);
  return (u16)((u + 0x7FFFu + ((u >> 16) & 1u)) >> 16);
}

// ---------------- FUSED amax over 4 tensors (segmented grid) ----------------
__global__ __launch_bounds__(256) void amax4_kernel(const float* __restrict__ x,
                                                    const float* __restrict__ w1,
                                                    const float* __restrict__ v1,
                                                    const float* __restrict__ w2,
                                                    unsigned* __restrict__ out) {
  const size_t nX = (size_t)4096 * 4096 / 4;
  const size_t nW = (size_t)10752 * 4096 / 4;
  int b = (int)blockIdx.x;
  const f32x4* p;
  size_t n4;
  int slot, b0, nb;
  if (b < 232)       { p = (const f32x4*)x;  n4 = nX; slot = 0; b0 = 0;    nb = 232; }
  else if (b < 840)  { p = (const f32x4*)w1; n4 = nW; slot = 1; b0 = 232;  nb = 608; }
  else if (b < 1448) { p = (const f32x4*)v1; n4 = nW; slot = 2; b0 = 840;  nb = 608; }
  else               { p = (const f32x4*)w2; n4 = nW; slot = 3; b0 = 1448; nb = 600; }
  float m = 0.0f;
  size_t stride = (size_t)nb * 256;
  for (size_t i = (size_t)(b - b0) * 256 + threadIdx.x; i < n4; i += stride) {
    f32x4 v = p[i];
    m = fmaxf(m, fmaxf(fmaxf(fabsf(v[0]), fabsf(v[1])), fmaxf(fabsf(v[2]), fabsf(v[3]))));
  }
#pragma unroll
  for (int off = 32; off > 0; off >>= 1) m = fmaxf(m, __shfl_down(m, off));
  __shared__ float red[4];
  int lane = threadIdx.x & 63, wid = threadIdx.x >> 6;
  if (lane == 0) red[wid] = m;
  __syncthreads();
  if (threadIdx.x == 0) {
    float v = fmaxf(fmaxf(red[0], red[1]), fmaxf(red[2], red[3]));
    atomicMax(out + slot, __float_as_uint(v));
  }
}

// ---------------- FUSED quantize w1+v1 f32 -> fp8 (segmented grid) ----------------
__global__ __launch_bounds__(256) void quant2_kernel(const float* __restrict__ w1,
                                                     u8* __restrict__ w1q,
                                                     const float* __restrict__ v1,
                                                     u8* __restrict__ v1q,
                                                     const unsigned* __restrict__ scal,
                                                     size_t n8) {
  int b = (int)blockIdx.x;
  const f32x4* p;
  uint2* q;
  float amax;
  int rb;
  if (b < 1024) { p = (const f32x4*)w1; q = (uint2*)w1q; amax = __uint_as_float(scal[1]); rb = b; }
  else          { p = (const f32x4*)v1; q = (uint2*)v1q; amax = __uint_as_float(scal[2]); rb = b - 1024; }
  float scale = 448.0f / fmaxf(amax, 1e-12f);
  size_t stride = (size_t)1024 * 256;
  for (size_t i = (size_t)rb * 256 + threadIdx.x; i < n8; i += stride) {
    f32x4 a = p[2 * i], c = p[2 * i + 1];
    uint2 r;
    r.x = cvt4_fp8(clamp448(a[0] * scale), clamp448(a[1] * scale),
                   clamp448(a[2] * scale), clamp448(a[3] * scale));
    r.y = cvt4_fp8(clamp448(c[0] * scale), clamp448(c[1] * scale),
                   clamp448(c[2] * scale), clamp448(c[3] * scale));
    q[i] = r;
  }
}

// ---------------- pack-quantize f32 [4096][K] -> fp8 Apk[K/32][4096][32] ----------------
__global__ __launch_bounds__(256) void pack_f32_kernel(const float* __restrict__ src,
                                                       u8* __restrict__ dst,
                                                       const unsigned* __restrict__ amax_bits,
                                                       int K) {
  float amax = __uint_as_float(*amax_bits);
  float scale = 448.0f / fmaxf(amax, 1e-12f);
  int c = (int)blockIdx.x * 256 + (int)threadIdx.x;
  int m = c & 4095;
  int kb = c >> 12;
  const f32x4* s = (const f32x4*)(src + (size_t)m * K + kb * 32);
  unsigned w[8];
#pragma unroll
  for (int j = 0; j < 8; ++j) {
    f32x4 v = s[j];
    w[j] = cvt4_fp8(clamp448(v[0] * scale), clamp448(v[1] * scale),
                    clamp448(v[2] * scale), clamp448(v[3] * scale));
  }
  u32x4* d = (u32x4*)(dst + ((size_t)kb * 4096 + m) * 32);
  d[0] = u32x4{w[0], w[1], w[2], w[3]};
  d[1] = u32x4{w[4], w[5], w[6], w[7]};
}

// ---------------- pack-quantize bf16 [4096][K] -> fp8 Apk[K/32][4096][32] ----------------
__global__ __launch_bounds__(256) void pack_bf16_kernel(const u16* __restrict__ src,
                                                        u8* __restrict__ dst,
                                                        const unsigned* __restrict__ amax_bits,
                                                        int K) {
  float amax = __uint_as_float(*amax_bits);
  float scale = 448.0f / fmaxf(amax, 1e-12f);
  int c = (int)blockIdx.x * 256 + (int)threadIdx.x;
  int m = c & 4095;
  int kb = c >> 12;
  const u16x8* s = (const u16x8*)(src + (size_t)m * K + kb * 32);
  unsigned w[8];
#pragma unroll
  for (int j = 0; j < 4; ++j) {
    u16x8 v = s[j];
    float f0 = __uint_as_float((unsigned)v[0] << 16) * scale;
    float f1 = __uint_as_float((unsigned)v[1] << 16) * scale;
    float f2 = __uint_as_float((unsigned)v[2] << 16) * scale;
    float f3 = __uint_as_float((unsigned)v[3] << 16) * scale;
    float f4 = __uint_as_float((unsigned)v[4] << 16) * scale;
    float f5 = __uint_as_float((unsigned)v[5] << 16) * scale;
    float f6 = __uint_as_float((unsigned)v[6] << 16) * scale;
    float f7 = __uint_as_float((unsigned)v[7] << 16) * scale;
    w[2 * j]     = cvt4_fp8(clamp448(f0), clamp448(f1), clamp448(f2), clamp448(f3));
    w[2 * j + 1] = cvt4_fp8(clamp448(f4), clamp448(f5), clamp448(f6), clamp448(f7));
  }
  u32x4* d = (u32x4*)(dst + ((size_t)kb * 4096 + m) * 32);
  d[0] = u32x4{w[0], w[1], w[2], w[3]};
  d[1] = u32x4{w[4], w[5], w[6], w[7]};
}

// ---------------- transpose + quantize: src [R][C] f32 -> dst [C][R] fp8 ----------------
__global__ __launch_bounds__(256) void quantT_kernel(const float* __restrict__ src,
                                                     u8* __restrict__ dst,
                                                     const unsigned* __restrict__ amax_bits,
                                                     int R, int C) {
  __shared__ float t[64][65];
  float amax = __uint_as_float(*amax_bits);
  float scale = 448.0f / fmaxf(amax, 1e-12f);
  int nbr = R >> 6;
  int br = (int)blockIdx.x % nbr, bc = (int)blockIdx.x / nbr;
  int r0 = br * 64, c0 = bc * 64;
  int tid = threadIdx.x;
  int lc = tid & 63, lr = tid >> 6;
#pragma unroll
  for (int i = 0; i < 16; ++i)
    t[lr + i * 4][lc] = src[(size_t)(r0 + lr + i * 4) * C + c0 + lc];
  __syncthreads();
  int qd = tid & 15, xbase = tid >> 4;
#pragma unroll
  for (int i = 0; i < 4; ++i) {
    int x = xbase + 16 * i;  // output row index (column of src tile)
    float v0 = clamp448(t[4 * qd + 0][x] * scale);
    float v1 = clamp448(t[4 * qd + 1][x] * scale);
    float v2 = clamp448(t[4 * qd + 2][x] * scale);
    float v3 = clamp448(t[4 * qd + 3][x] * scale);
    *(unsigned*)(dst + (size_t)(c0 + x) * R + r0 + 4 * qd) = cvt4_fp8(v0, v1, v2, v3);
  }
}

// ---------------- LDS address swizzle ----------------
// 16B-block XOR within 64B row, key = (row>>2)&3 (verified conflict-free
// rounds 3/5/6/8/11/13/14/15: SQ_LDS_BANK_CONFLICT == 0).
__device__ __forceinline__ int swz_key(int r) { return (r >> 2) & 3; }

__device__ __forceinline__ int swz_off32(int r, int h) {
  return r * 64 + ((((h << 1) ^ swz_key(r)) << 4));
}

// Load a 32B MX-fp8 fragment (k-half h of row r) from a swizzled [*][64] tile.
__device__ __forceinline__ i32x8 ld_frag(const u8* base, int r, int h) {
  int o = swz_off32(r, h);
  i32x8 f;
  f.lo = *(const i32x4*)(base + o);
  f.hi = *(const i32x4*)(base + (o ^ 16));
  return f;
}

// Load a 32B packed-A fragment straight from global (coalesced).
__device__ __forceinline__ i32x8 ld_a_g(const u8* p) {
  i32x8 f;
  f.lo = *(const i32x4*)p;
  f.hi = *(const i32x4*)(p + 16);
  return f;
}

#define MFMA_MX(a, b, c) \
  __builtin_amdgcn_mfma_scale_f32_32x32x64_f8f6f4((a), (b), (c), 0, 0, 0, 0x7F7F7F7F, 0, 0x7F7F7F7F)

// ---------------- GEMM1: gate/up fused, NT, MX-fp8, 128x128, 4 waves ----------------
// r15 + MERGED PHASE: one 8-MFMA cluster, 2 barriers per K-step (was 4).
// vmcnt audit unchanged: per-iter VMEM issue = A-pref(4) + stages(4) = 8;
// at B0 of iter t, iter t-1's 8 are the allowed-outstanding -> everything
// from iter t-2 (incl. stage(t)) is retired, regardless of intra-iter order.
// B0 after the wait makes tile-t LDS visibility block-wide (r9 race fix).
// MFMA accumulation order per accumulator unchanged -> bit-identical output.
__global__ __launch_bounds__(256, 2) void gemm1_gateup(
    const u8* __restrict__ Apk, const u8* __restrict__ Wq, const u8* __restrict__ Vq,
    const unsigned* __restrict__ scal, u16* __restrict__ inter,
    unsigned* __restrict__ amax_mid, int M, int N, int K) {
  __shared__ __align__(16) u8 lW[3][8192], lV[3][8192];
  __shared__ float red[4];
  int tid = threadIdx.x;
  int lane = tid & 63, wid = tid >> 6;
  int wm = wid >> 1, wn = wid & 1;  // 2M x 2N waves, per-wave 64x64 dual

  int bid = (int)blockIdx.x;
  int bm = bid & 31;                // M/128 == 32; bn-major (r14: L2/L3 residency)
  int bn = bid >> 5;

  int r0 = tid >> 2;                           // 0..63
  int kblk = ((tid & 3) ^ swz_key(r0)) << 4;   // pre-swizzled global source chunk
  const u8* wS = Wq + (size_t)(bn * 128 + r0) * K + kblk;
  const u8* vS = Vq + (size_t)(bn * 128 + r0) * K + kblk;
  size_t rK = (size_t)64 * K;                  // rows 64..127 (key period 16 -> same kblk)

  f32x16 g00 = (f32x16)(0.f), g01 = (f32x16)(0.f), g10 = (f32x16)(0.f), g11 = (f32x16)(0.f);
  f32x16 u00 = (f32x16)(0.f), u01 = (f32x16)(0.f), u10 = (f32x16)(0.f), u11 = (f32x16)(0.f);

  int rfrag = lane & 31;
  int h = lane >> 5;
  int arow = wm * 64 + rfrag;
  int brow = wn * 64 + rfrag;

  // packed-A: addr(t,h,r) = ((2t+h)*M + r)*32
  const size_t tStride = (size_t)64 * M;
  const u8* aP = Apk + 32 * ((size_t)M * h + (size_t)(bm * 128 + arow));

  int NT = K >> 6;
  // prologue: stage W/V tiles 0,1 (4 loads each); A-frags for tile 0
  {
    gload_lds16(wS + 0, lW[0] + tid * 16);
    gload_lds16(wS + 0 + rK, lW[0] + 4096 + tid * 16);
    gload_lds16(vS + 0, lV[0] + tid * 16);
    gload_lds16(vS + 0 + rK, lV[0] + 4096 + tid * 16);
    gload_lds16(wS + 64, lW[1] + tid * 16);
    gload_lds16(wS + 64 + rK, lW[1] + 4096 + tid * 16);
    gload_lds16(vS + 64, lV[1] + tid * 16);
    gload_lds16(vS + 64 + rK, lV[1] + 4096 + tid * 16);
  }
  i32x8 ac0 = ld_a_g(aP);
  i32x8 ac1 = ld_a_g(aP + 1024);
  i32x8 an0 = ac0, an1 = ac1;

  for (int t = 0; t < NT; ++t) {
    int cur = t % 3;
    int nx = cur + 2; if (nx >= 3) nx -= 3;   // (t+2)%3
    int kt2 = (t + 2) * 64;
    bool do_stage = (t + 2) < NT;
    bool do_pref = (t + 1) < NT;
    if (do_pref) {
      asm volatile("s_waitcnt vmcnt(8)" ::: "memory");
    } else {
      asm volatile("s_waitcnt vmcnt(0)" ::: "memory");
    }
    __builtin_amdgcn_s_barrier();   // B0 (race fix)
    // ---- single merged phase ----
    i32x8 w0 = ld_frag(lW[cur], brow, h);
    i32x8 w1 = ld_frag(lW[cur], brow + 32, h);
    i32x8 v0 = ld_frag(lV[cur], brow, h);
    i32x8 v1 = ld_frag(lV[cur], brow + 32, h);
    if (do_pref) {                  // packed-A prefetch for t+1 (own-wave regs)
      const u8* ap = aP + (size_t)(t + 1) * tStride;
      an0 = ld_a_g(ap);
      an1 = ld_a_g(ap + 1024);
    }
    if (do_stage) {
      gload_lds16(wS + kt2, lW[nx] + tid * 16);
      gload_lds16(wS + kt2 + rK, lW[nx] + 4096 + tid * 16);
      gload_lds16(vS + kt2, lV[nx] + tid * 16);
      gload_lds16(vS + kt2 + rK, lV[nx] + 4096 + tid * 16);
    }
    __builtin_amdgcn_s_barrier();   // B1
    __builtin_amdgcn_s_setprio(1);
    g00 = MFMA_MX(ac0, w0, g00);
    g10 = MFMA_MX(ac1, w0, g10);
    g01 = MFMA_MX(ac0, w1, g01);
    g11 = MFMA_MX(ac1, w1, g11);
    u00 = MFMA_MX(ac0, v0, u00);
    u10 = MFMA_MX(ac1, v0, u10);
    u01 = MFMA_MX(ac0, v1, u01);
    u11 = MFMA_MX(ac1, v1, u11);
    __builtin_amdgcn_s_setprio(0);
    ac0 = an0; ac1 = an1;           // advance A pipeline
    // next iteration's B0 doubles as the trailing barrier
  }

  float ax = __uint_as_float(scal[0]);
  float aw = __uint_as_float(scal[1]);
  float av = __uint_as_float(scal[2]);
  float inv_x = 1.0f / (448.0f / fmaxf(ax, 1e-12f));
  float inv_w = 1.0f / (448.0f / fmaxf(aw, 1e-12f));
  float inv_v = 1.0f / (448.0f / fmaxf(av, 1e-12f));
  float sg = inv_x * inv_w, su = inv_x * inv_v;

  // C/D layout 32x32: col = lane&31, row = (reg&3) + 8*(reg>>2) + 4*(lane>>5)
  int rb = bm * 128 + wm * 64 + h * 4;
  int cb = bn * 128 + wn * 64 + rfrag;
  float lmax = 0.0f;
#pragma unroll
  for (int mi = 0; mi < 2; ++mi)
#pragma unroll
    for (int ni = 0; ni < 2; ++ni) {
      const f32x16& gg = mi ? (ni ? g11 : g10) : (ni ? g01 : g00);
      const f32x16& uu = mi ? (ni ? u11 : u10) : (ni ? u01 : u00);
#pragma unroll
      for (int q = 0; q < 16; ++q) {
        int rr = rb + mi * 32 + (q & 3) + 8 * (q >> 2);
        float gv = gg[q] * sg;
        float uv = uu[q] * su;
        float iv = gv / (1.0f + expf(-gv)) * uv;  // silu(g)*u
        inter[(size_t)rr * N + (cb + ni * 32)] = f32_to_bf16(iv);
        lmax = fmaxf(lmax, fabsf(iv));
      }
    }
#pragma unroll
  for (int off = 32; off > 0; off >>= 1) lmax = fmaxf(lmax, __shfl_down(lmax, off));
  if (lane == 0) red[wid] = lmax;
  __syncthreads();
  if (tid == 0)
    atomicMax(amax_mid, __float_as_uint(fmaxf(fmaxf(red[0], red[1]), fmaxf(red[2], red[3]))));
}

// ---------------- GEMM2: down proj, NT vs pre-transposed w2, 128x128 ----------------
// Merged phase (4-MFMA cluster, 2 barriers/K-step). Per-iter VMEM =
// aPref(4)+stB(2) = 6 -> vmcnt(6); same outstanding-set audit as gemm1.
__global__ __launch_bounds__(256, 2) void gemm2_down(
    const u8* __restrict__ Apk, const u8* __restrict__ Bq,
    const unsigned* __restrict__ amax_a, const unsigned* __restrict__ amax_b,
    float* __restrict__ out, int M, int N, int K) {
  __shared__ __align__(16) u8 lB[3][8192];
  int tid = threadIdx.x;
  int lane = tid & 63, wid = tid >> 6;
  int wm = wid >> 1, wn = wid & 1;

  int bid = (int)blockIdx.x;
  int bm = bid & 31;                // M/128 == 32; bn-major
  int bn = bid >> 5;

  int r0 = tid >> 2;
  int kblk = ((tid & 3) ^ swz_key(r0)) << 4;
  const u8* bS = Bq + (size_t)(bn * 128 + r0) * K + kblk;
  size_t rK = (size_t)64 * K;

  f32x16 c00 = (f32x16)(0.f), c01 = (f32x16)(0.f);
  f32x16 c10 = (f32x16)(0.f), c11 = (f32x16)(0.f);

  int rfrag = lane & 31;
  int h = lane >> 5;
  int arow = wm * 64 + rfrag;
  int brow = wn * 64 + rfrag;

  const size_t tStride = (size_t)64 * M;
  const u8* aP = Apk + 32 * ((size_t)M * h + (size_t)(bm * 128 + arow));

  int NT = K >> 6;
  {
    gload_lds16(bS + 0, lB[0] + tid * 16);
    gload_lds16(bS + 0 + rK, lB[0] + 4096 + tid * 16);
    gload_lds16(bS + 64, lB[1] + tid * 16);
    gload_lds16(bS + 64 + rK, lB[1] + 4096 + tid * 16);
  }
  i32x8 ac0 = ld_a_g(aP);
  i32x8 ac1 = ld_a_g(aP + 1024);
  i32x8 an0 = ac0, an1 = ac1;

  for (int t = 0; t < NT; ++t) {
    int cur = t % 3;
    int nx = cur + 2; if (nx >= 3) nx -= 3;
    int kt2 = (t + 2) * 64;
    bool do_stage = (t + 2) < NT;
    bool do_pref = (t + 1) < NT;
    if (do_pref) {
      asm volatile("s_waitcnt vmcnt(6)" ::: "memory");
    } else {
      asm volatile("s_waitcnt vmcnt(0)" ::: "memory");
    }
    __builtin_amdgcn_s_barrier();   // B0 (race fix)
    // ---- single merged phase ----
    i32x8 b0 = ld_frag(lB[cur], brow, h);
    i32x8 b1 = ld_frag(lB[cur], brow + 32, h);
    if (do_pref) {
      const u8* ap = aP + (size_t)(t + 1) * tStride;
      an0 = ld_a_g(ap);
      an1 = ld_a_g(ap + 1024);
    }
    if (do_stage) {
      gload_lds16(bS + kt2, lB[nx] + tid * 16);
      gload_lds16(bS + kt2 + rK, lB[nx] + 4096 + tid * 16);
    }
    __builtin_amdgcn_s_barrier();
    __builtin_amdgcn_s_setprio(1);
    c00 = MFMA_MX(ac0, b0, c00);
    c10 = MFMA_MX(ac1, b0, c10);
    c01 = MFMA_MX(ac0, b1, c01);
    c11 = MFMA_MX(ac1, b1, c11);
    __builtin_amdgcn_s_setprio(0);
    ac0 = an0; ac1 = an1;
  }

  float sa = 1.0f / (448.0f / fmaxf(__uint_as_float(*amax_a), 1e-12f));
  float sb = 1.0f / (448.0f / fmaxf(__uint_as_float(*amax_b), 1e-12f));
  float sc = sa * sb;

  int rb = bm * 128 + wm * 64 + h * 4;
  int cb = bn * 128 + wn * 64 + rfrag;
#pragma unroll
  for (int mi = 0; mi < 2; ++mi)
#pragma unroll
    for (int ni = 0; ni < 2; ++ni) {
      const f32x16& cc = mi ? (ni ? c11 : c10) : (ni ? c01 : c00);
#pragma unroll
      for (int q = 0; q < 16; ++q) {
        int rr = rb + mi * 32 + (q & 3) + 8 * (q >> 2);
        out[(size_t)rr * N + (cb + ni * 32)] = cc[q] * sc;
      }
    }
}

// ---------------- host launcher ----------------
extern "C" void kernel_launch(void* const* d_in, const int* in_sizes, int n_in,
                              void* d_out, int out_size, void* d_ws, size_t ws_size,
                              hipStream_t stream) {
  const float* x  = (const float*)d_in[0];
  const float* w1 = (const float*)d_in[1];
  const float* v1 = (const float*)d_in[2];
  const float* w2 = (const float*)d_in[3];
  const int M = 4096, H = 4096, F = 10752;

  u8* ws = (u8*)d_ws;
  unsigned* scal = (unsigned*)ws;          // [0]=x [1]=w1 [2]=v1 [3]=w2 [4]=mid
  u8* xpk  = ws + 256;                     // packed A for gemm1 [H/32][M][32]
  u8* w1q  = xpk  + (size_t)M * H;
  u8* v1q  = w1q  + (size_t)F * H;
  u8* w2qT = v1q  + (size_t)F * H;
  u8* midpk = w2qT + (size_t)F * H;        // packed A for gemm2 [F/32][M][32]
  u16* inter = (u16*)(midpk + (size_t)M * F);  // bf16 inter

  hipMemsetAsync(scal, 0, 256, stream);
  amax4_kernel<<<2048, 256, 0, stream>>>(x, w1, v1, w2, scal);

  pack_f32_kernel<<<(M * (H / 32)) / 256, 256, 0, stream>>>(x, xpk, scal + 0, H);
  quant2_kernel<<<2048, 256, 0, stream>>>(w1, w1q, v1, v1q, scal, (size_t)F * H / 8);
  quantT_kernel<<<(F / 64) * (H / 64), 256, 0, stream>>>(w2, w2qT, scal + 3, F, H);

  gemm1_gateup<<<(M / 128) * (F / 128), 256, 0, stream>>>(xpk, w1q, v1q, scal, inter,
                                                          scal + 4, M, F, H);
  pack_bf16_kernel<<<(M * (F / 32)) / 256, 256, 0, stream>>>(inter, midpk, scal + 4, F);
  gemm2_down<<<(M / 128) * (H / 128), 256, 0, stream>>>(midpk, w2qT, scal + 4, scal + 3,
                                                        (float*)d_out, M, H, F);
}

// Round 17
// 893.765 us; speedup vs baseline: 1.4638x; 1.0914x over previous
//
#include <hip/hip_runtime.h>
#include <cstdint>
#include <cstddef>

typedef float f32x4 __attribute__((ext_vector_type(4)));
typedef float f32x16 __attribute__((ext_vector_type(16)));
typedef int i32x4 __attribute__((ext_vector_type(4)));
typedef int i32x8 __attribute__((ext_vector_type(8)));
typedef unsigned char u8;
typedef unsigned short u16;
typedef u16 u16x8 __attribute__((ext_vector_type(8)));
typedef unsigned int u32;
typedef u32 u32x4 __attribute__((ext_vector_type(4)));

// ---------------- async global->LDS (16B per lane, linear dest) ----------------
static __device__ __forceinline__ void gload_lds16(const void* g, void* l) {
  __builtin_amdgcn_global_load_lds(
      (__attribute__((address_space(1))) void*)(void*)g,
      (__attribute__((address_space(3))) void*)l,
      16, 0, 0);
}

// ---------------- fp8 e4m3fn (OCP) conversion, RNE ----------------
#if defined(__has_builtin)
#if __has_builtin(__builtin_amdgcn_cvt_pk_fp8_f32)
#define HAVE_HW_FP8 1
#endif
#endif

__device__ __forceinline__ u8 f32_to_e4m3_sw(float x) {
  unsigned s = (__float_as_uint(x) >> 24) & 0x80;
  float ax = fabsf(x);
  if (!(ax > 0.0f)) return (u8)s;
  if (ax >= 448.0f) return (u8)(s | 0x7e);
  if (ax < 0.015625f) {            // subnormal, step 2^-9
    int m = (int)rintf(ax * 512.0f);
    if (m >= 8) return (u8)(s | 0x08);
    return (u8)(s | m);
  }
  int e = ilogbf(ax);
  int m = (int)rintf(ldexpf(ax, 3 - e));
  if (m == 16) { ++e; m = 8; }
  return (u8)(s | ((e + 7) << 3) | (m - 8));
}

__device__ __forceinline__ unsigned cvt4_fp8(float a, float b, float c, float d) {
#ifdef HAVE_HW_FP8
  int lo = __builtin_amdgcn_cvt_pk_fp8_f32(a, b, 0, false);
  return (unsigned)__builtin_amdgcn_cvt_pk_fp8_f32(c, d, lo, true);
#else
  return (unsigned)f32_to_e4m3_sw(a) | ((unsigned)f32_to_e4m3_sw(b) << 8) |
         ((unsigned)f32_to_e4m3_sw(c) << 16) | ((unsigned)f32_to_e4m3_sw(d) << 24);
#endif
}

__device__ __forceinline__ float clamp448(float x) {
  return fminf(fmaxf(x, -448.f), 448.f);
}

__device__ __forceinline__ u16 f32_to_bf16(float x) {  // RNE
  unsigned u = __float_as_uint(x);
  return (u16)((u + 0x7FFFu + ((u >> 16) & 1u)) >> 16);
}

// ---------------- FUSED amax over 4 tensors (segmented grid) ----------------
__global__ __launch_bounds__(256) void amax4_kernel(const float* __restrict__ x,
                                                    const float* __restrict__ w1,
                                                    const float* __restrict__ v1,
                                                    const float* __restrict__ w2,
                                                    unsigned* __restrict__ out) {
  const size_t nX = (size_t)4096 * 4096 / 4;
  const size_t nW = (size_t)10752 * 4096 / 4;
  int b = (int)blockIdx.x;
  const f32x4* p;
  size_t n4;
  int slot, b0, nb;
  if (b < 232)       { p = (const f32x4*)x;  n4 = nX; slot = 0; b0 = 0;    nb = 232; }
  else if (b < 840)  { p = (const f32x4*)w1; n4 = nW; slot = 1; b0 = 232;  nb = 608; }
  else if (b < 1448) { p = (const f32x4*)v1; n4 = nW; slot = 2; b0 = 840;  nb = 608; }
  else               { p = (const f32x4*)w2; n4 = nW; slot = 3; b0 = 1448; nb = 600; }
  float m = 0.0f;
  size_t stride = (size_t)nb * 256;
  for (size_t i = (size_t)(b - b0) * 256 + threadIdx.x; i < n4; i += stride) {
    f32x4 v = p[i];
    m = fmaxf(m, fmaxf(fmaxf(fabsf(v[0]), fabsf(v[1])), fmaxf(fabsf(v[2]), fabsf(v[3]))));
  }
#pragma unroll
  for (int off = 32; off > 0; off >>= 1) m = fmaxf(m, __shfl_down(m, off));
  __shared__ float red[4];
  int lane = threadIdx.x & 63, wid = threadIdx.x >> 6;
  if (lane == 0) red[wid] = m;
  __syncthreads();
  if (threadIdx.x == 0) {
    float v = fmaxf(fmaxf(red[0], red[1]), fmaxf(red[2], red[3]));
    atomicMax(out + slot, __float_as_uint(v));
  }
}

// ---------------- FUSED quantize w1+v1 f32 -> fp8 (segmented grid) ----------------
__global__ __launch_bounds__(256) void quant2_kernel(const float* __restrict__ w1,
                                                     u8* __restrict__ w1q,
                                                     const float* __restrict__ v1,
                                                     u8* __restrict__ v1q,
                                                     const unsigned* __restrict__ scal,
                                                     size_t n8) {
  int b = (int)blockIdx.x;
  const f32x4* p;
  uint2* q;
  float amax;
  int rb;
  if (b < 1024) { p = (const f32x4*)w1; q = (uint2*)w1q; amax = __uint_as_float(scal[1]); rb = b; }
  else          { p = (const f32x4*)v1; q = (uint2*)v1q; amax = __uint_as_float(scal[2]); rb = b - 1024; }
  float scale = 448.0f / fmaxf(amax, 1e-12f);
  size_t stride = (size_t)1024 * 256;
  for (size_t i = (size_t)rb * 256 + threadIdx.x; i < n8; i += stride) {
    f32x4 a = p[2 * i], c = p[2 * i + 1];
    uint2 r;
    r.x = cvt4_fp8(clamp448(a[0] * scale), clamp448(a[1] * scale),
                   clamp448(a[2] * scale), clamp448(a[3] * scale));
    r.y = cvt4_fp8(clamp448(c[0] * scale), clamp448(c[1] * scale),
                   clamp448(c[2] * scale), clamp448(c[3] * scale));
    q[i] = r;
  }
}

// ---------------- pack-quantize f32 [4096][K] -> fp8 Apk[K/32][4096][32] ----------------
__global__ __launch_bounds__(256) void pack_f32_kernel(const float* __restrict__ src,
                                                       u8* __restrict__ dst,
                                                       const unsigned* __restrict__ amax_bits,
                                                       int K) {
  float amax = __uint_as_float(*amax_bits);
  float scale = 448.0f / fmaxf(amax, 1e-12f);
  int c = (int)blockIdx.x * 256 + (int)threadIdx.x;
  int m = c & 4095;
  int kb = c >> 12;
  const f32x4* s = (const f32x4*)(src + (size_t)m * K + kb * 32);
  unsigned w[8];
#pragma unroll
  for (int j = 0; j < 8; ++j) {
    f32x4 v = s[j];
    w[j] = cvt4_fp8(clamp448(v[0] * scale), clamp448(v[1] * scale),
                    clamp448(v[2] * scale), clamp448(v[3] * scale));
  }
  u32x4* d = (u32x4*)(dst + ((size_t)kb * 4096 + m) * 32);
  d[0] = u32x4{w[0], w[1], w[2], w[3]};
  d[1] = u32x4{w[4], w[5], w[6], w[7]};
}

// ---------------- pack-quantize bf16 [4096][K] -> fp8 Apk[K/32][4096][32] ----------------
__global__ __launch_bounds__(256) void pack_bf16_kernel(const u16* __restrict__ src,
                                                        u8* __restrict__ dst,
                                                        const unsigned* __restrict__ amax_bits,
                                                        int K) {
  float amax = __uint_as_float(*amax_bits);
  float scale = 448.0f / fmaxf(amax, 1e-12f);
  int c = (int)blockIdx.x * 256 + (int)threadIdx.x;
  int m = c & 4095;
  int kb = c >> 12;
  const u16x8* s = (const u16x8*)(src + (size_t)m * K + kb * 32);
  unsigned w[8];
#pragma unroll
  for (int j = 0; j < 4; ++j) {
    u16x8 v = s[j];
    float f0 = __uint_as_float((unsigned)v[0] << 16) * scale;
    float f1 = __uint_as_float((unsigned)v[1] << 16) * scale;
    float f2 = __uint_as_float((unsigned)v[2] << 16) * scale;
    float f3 = __uint_as_float((unsigned)v[3] << 16) * scale;
    float f4 = __uint_as_float((unsigned)v[4] << 16) * scale;
    float f5 = __uint_as_float((unsigned)v[5] << 16) * scale;
    float f6 = __uint_as_float((unsigned)v[6] << 16) * scale;
    float f7 = __uint_as_float((unsigned)v[7] << 16) * scale;
    w[2 * j]     = cvt4_fp8(clamp448(f0), clamp448(f1), clamp448(f2), clamp448(f3));
    w[2 * j + 1] = cvt4_fp8(clamp448(f4), clamp448(f5), clamp448(f6), clamp448(f7));
  }
  u32x4* d = (u32x4*)(dst + ((size_t)kb * 4096 + m) * 32);
  d[0] = u32x4{w[0], w[1], w[2], w[3]};
  d[1] = u32x4{w[4], w[5], w[6], w[7]};
}

// ---------------- transpose + quantize: src [R][C] f32 -> dst [C][R] fp8 ----------------
__global__ __launch_bounds__(256) void quantT_kernel(const float* __restrict__ src,
                                                     u8* __restrict__ dst,
                                                     const unsigned* __restrict__ amax_bits,
                                                     int R, int C) {
  __shared__ float t[64][65];
  float amax = __uint_as_float(*amax_bits);
  float scale = 448.0f / fmaxf(amax, 1e-12f);
  int nbr = R >> 6;
  int br = (int)blockIdx.x % nbr, bc = (int)blockIdx.x / nbr;
  int r0 = br * 64, c0 = bc * 64;
  int tid = threadIdx.x;
  int lc = tid & 63, lr = tid >> 6;
#pragma unroll
  for (int i = 0; i < 16; ++i)
    t[lr + i * 4][lc] = src[(size_t)(r0 + lr + i * 4) * C + c0 + lc];
  __syncthreads();
  int qd = tid & 15, xbase = tid >> 4;
#pragma unroll
  for (int i = 0; i < 4; ++i) {
    int x = xbase + 16 * i;  // output row index (column of src tile)
    float v0 = clamp448(t[4 * qd + 0][x] * scale);
    float v1 = clamp448(t[4 * qd + 1][x] * scale);
    float v2 = clamp448(t[4 * qd + 2][x] * scale);
    float v3 = clamp448(t[4 * qd + 3][x] * scale);
    *(unsigned*)(dst + (size_t)(c0 + x) * R + r0 + 4 * qd) = cvt4_fp8(v0, v1, v2, v3);
  }
}

// ---------------- LDS address swizzle ----------------
// 16B-block XOR within 64B row, key = (row>>2)&3 (verified conflict-free
// rounds 3/5/6/8/11/13/14/15/16: SQ_LDS_BANK_CONFLICT == 0).
__device__ __forceinline__ int swz_key(int r) { return (r >> 2) & 3; }

__device__ __forceinline__ int swz_off32(int r, int h) {
  return r * 64 + ((((h << 1) ^ swz_key(r)) << 4));
}

// Load a 32B MX-fp8 fragment (k-half h of row r) from a swizzled [*][64] tile.
__device__ __forceinline__ i32x8 ld_frag(const u8* base, int r, int h) {
  int o = swz_off32(r, h);
  i32x8 f;
  f.lo = *(const i32x4*)(base + o);
  f.hi = *(const i32x4*)(base + (o ^ 16));
  return f;
}

// Load a 32B packed-A fragment straight from global (coalesced).
__device__ __forceinline__ i32x8 ld_a_g(const u8* p) {
  i32x8 f;
  f.lo = *(const i32x4*)p;
  f.hi = *(const i32x4*)(p + 16);
  return f;
}

#define MFMA_MX(a, b, c) \
  __builtin_amdgcn_mfma_scale_f32_32x32x64_f8f6f4((a), (b), (c), 0, 0, 0, 0x7F7F7F7F, 0, 0x7F7F7F7F)

// ---------------- GEMM1: gate/up fused, NT, MX-fp8, 128x128, 4 waves ----------------
// r16 structure EXACTLY (best measured: 426 us): merged 8-MFMA cluster,
// tri-buffer W/V LDS, packed-A from global, counted vmcnt(8) + B0 race-fix,
// bn-major block order (L2/L3 residency).
__global__ __launch_bounds__(256, 2) void gemm1_gateup(
    const u8* __restrict__ Apk, const u8* __restrict__ Wq, const u8* __restrict__ Vq,
    const unsigned* __restrict__ scal, u16* __restrict__ inter,
    unsigned* __restrict__ amax_mid, int M, int N, int K) {
  __shared__ __align__(16) u8 lW[3][8192], lV[3][8192];
  __shared__ float red[4];
  int tid = threadIdx.x;
  int lane = tid & 63, wid = tid >> 6;
  int wm = wid >> 1, wn = wid & 1;  // 2M x 2N waves, per-wave 64x64 dual

  int bid = (int)blockIdx.x;
  int bm = bid & 31;                // M/128 == 32; bn-major (r14: L2/L3 residency)
  int bn = bid >> 5;

  int r0 = tid >> 2;                           // 0..63
  int kblk = ((tid & 3) ^ swz_key(r0)) << 4;   // pre-swizzled global source chunk
  const u8* wS = Wq + (size_t)(bn * 128 + r0) * K + kblk;
  const u8* vS = Vq + (size_t)(bn * 128 + r0) * K + kblk;
  size_t rK = (size_t)64 * K;                  // rows 64..127 (key period 16 -> same kblk)

  f32x16 g00 = (f32x16)(0.f), g01 = (f32x16)(0.f), g10 = (f32x16)(0.f), g11 = (f32x16)(0.f);
  f32x16 u00 = (f32x16)(0.f), u01 = (f32x16)(0.f), u10 = (f32x16)(0.f), u11 = (f32x16)(0.f);

  int rfrag = lane & 31;
  int h = lane >> 5;
  int arow = wm * 64 + rfrag;
  int brow = wn * 64 + rfrag;

  // packed-A: addr(t,h,r) = ((2t+h)*M + r)*32
  const size_t tStride = (size_t)64 * M;
  const u8* aP = Apk + 32 * ((size_t)M * h + (size_t)(bm * 128 + arow));

  int NT = K >> 6;
  // prologue: stage W/V tiles 0,1 (4 loads each); A-frags for tile 0
  {
    gload_lds16(wS + 0, lW[0] + tid * 16);
    gload_lds16(wS + 0 + rK, lW[0] + 4096 + tid * 16);
    gload_lds16(vS + 0, lV[0] + tid * 16);
    gload_lds16(vS + 0 + rK, lV[0] + 4096 + tid * 16);
    gload_lds16(wS + 64, lW[1] + tid * 16);
    gload_lds16(wS + 64 + rK, lW[1] + 4096 + tid * 16);
    gload_lds16(vS + 64, lV[1] + tid * 16);
    gload_lds16(vS + 64 + rK, lV[1] + 4096 + tid * 16);
  }
  i32x8 ac0 = ld_a_g(aP);
  i32x8 ac1 = ld_a_g(aP + 1024);
  i32x8 an0 = ac0, an1 = ac1;

  for (int t = 0; t < NT; ++t) {
    int cur = t % 3;
    int nx = cur + 2; if (nx >= 3) nx -= 3;   // (t+2)%3
    int kt2 = (t + 2) * 64;
    bool do_stage = (t + 2) < NT;
    bool do_pref = (t + 1) < NT;
    if (do_pref) {
      asm volatile("s_waitcnt vmcnt(8)" ::: "memory");
    } else {
      asm volatile("s_waitcnt vmcnt(0)" ::: "memory");
    }
    __builtin_amdgcn_s_barrier();   // B0 (race fix)
    // ---- single merged phase ----
    i32x8 w0 = ld_frag(lW[cur], brow, h);
    i32x8 w1 = ld_frag(lW[cur], brow + 32, h);
    i32x8 v0 = ld_frag(lV[cur], brow, h);
    i32x8 v1 = ld_frag(lV[cur], brow + 32, h);
    if (do_pref) {                  // packed-A prefetch for t+1 (own-wave regs)
      const u8* ap = aP + (size_t)(t + 1) * tStride;
      an0 = ld_a_g(ap);
      an1 = ld_a_g(ap + 1024);
    }
    if (do_stage) {
      gload_lds16(wS + kt2, lW[nx] + tid * 16);
      gload_lds16(wS + kt2 + rK, lW[nx] + 4096 + tid * 16);
      gload_lds16(vS + kt2, lV[nx] + tid * 16);
      gload_lds16(vS + kt2 + rK, lV[nx] + 4096 + tid * 16);
    }
    __builtin_amdgcn_s_barrier();   // B1
    __builtin_amdgcn_s_setprio(1);
    g00 = MFMA_MX(ac0, w0, g00);
    g10 = MFMA_MX(ac1, w0, g10);
    g01 = MFMA_MX(ac0, w1, g01);
    g11 = MFMA_MX(ac1, w1, g11);
    u00 = MFMA_MX(ac0, v0, u00);
    u10 = MFMA_MX(ac1, v0, u10);
    u01 = MFMA_MX(ac0, v1, u01);
    u11 = MFMA_MX(ac1, v1, u11);
    __builtin_amdgcn_s_setprio(0);
    ac0 = an0; ac1 = an1;           // advance A pipeline
    // next iteration's B0 doubles as the trailing barrier
  }

  float ax = __uint_as_float(scal[0]);
  float aw = __uint_as_float(scal[1]);
  float av = __uint_as_float(scal[2]);
  float inv_x = 1.0f / (448.0f / fmaxf(ax, 1e-12f));
  float inv_w = 1.0f / (448.0f / fmaxf(aw, 1e-12f));
  float inv_v = 1.0f / (448.0f / fmaxf(av, 1e-12f));
  float sg = inv_x * inv_w, su = inv_x * inv_v;

  // C/D layout 32x32: col = lane&31, row = (reg&3) + 8*(reg>>2) + 4*(lane>>5)
  int rb = bm * 128 + wm * 64 + h * 4;
  int cb = bn * 128 + wn * 64 + rfrag;
  float lmax = 0.0f;
#pragma unroll
  for (int mi = 0; mi < 2; ++mi)
#pragma unroll
    for (int ni = 0; ni < 2; ++ni) {
      const f32x16& gg = mi ? (ni ? g11 : g10) : (ni ? g01 : g00);
      const f32x16& uu = mi ? (ni ? u11 : u10) : (ni ? u01 : u00);
#pragma unroll
      for (int q = 0; q < 16; ++q) {
        int rr = rb + mi * 32 + (q & 3) + 8 * (q >> 2);
        float gv = gg[q] * sg;
        float uv = uu[q] * su;
        float iv = gv / (1.0f + expf(-gv)) * uv;  // silu(g)*u
        inter[(size_t)rr * N + (cb + ni * 32)] = f32_to_bf16(iv);
        lmax = fmaxf(lmax, fabsf(iv));
      }
    }
#pragma unroll
  for (int off = 32; off > 0; off >>= 1) lmax = fmaxf(lmax, __shfl_down(lmax, off));
  if (lane == 0) red[wid] = lmax;
  __syncthreads();
  if (tid == 0)
    atomicMax(amax_mid, __float_as_uint(fmaxf(fmaxf(red[0], red[1]), fmaxf(red[2], red[3]))));
}

// ---------------- GEMM2: down proj, NT vs pre-transposed w2, 128x256 ----------------
// BN widened 128->256: per-wave 64x128 (4 N-frags), 8-MFMA cluster per
// barrier-pair — matches gemm1's measured-best MFMA:barrier density (r16:
// gemm2 at BN=128 had half the density and ran ~1.5x its FLOP-proportional
// time). Ledger identical to gemm1: per-iter VMEM = A-pref(4)+stage(4)=8 ->
// vmcnt(8); B0 after wait (r9 race fix). Per-accumulator K-order unchanged
// -> bit-identical output. lB tri-buffer 16KB/tile = 48KB -> 2 blocks/CU.
__global__ __launch_bounds__(256, 2) void gemm2_down(
    const u8* __restrict__ Apk, const u8* __restrict__ Bq,
    const unsigned* __restrict__ amax_a, const unsigned* __restrict__ amax_b,
    float* __restrict__ out, int M, int N, int K) {
  __shared__ __align__(16) u8 lB[3][16384];
  int tid = threadIdx.x;
  int lane = tid & 63, wid = tid >> 6;
  int wm = wid >> 1, wn = wid & 1;  // 2M x 2N waves, per-wave 64x128

  int bid = (int)blockIdx.x;
  int bm = bid & 31;                // M/128 == 32; bn-major
  int bn = bid >> 5;                // N/256 == 16

  int r0 = tid >> 2;                // 0..63
  int kblk = ((tid & 3) ^ swz_key(r0)) << 4;
  const u8* bS = Bq + (size_t)(bn * 256 + r0) * K + kblk;
  size_t rK = (size_t)64 * K;       // +64 rows (key period 16 -> same kblk)

  f32x16 d00 = (f32x16)(0.f), d01 = (f32x16)(0.f), d02 = (f32x16)(0.f), d03 = (f32x16)(0.f);
  f32x16 d10 = (f32x16)(0.f), d11 = (f32x16)(0.f), d12 = (f32x16)(0.f), d13 = (f32x16)(0.f);

  int rfrag = lane & 31;
  int h = lane >> 5;
  int arow = wm * 64 + rfrag;
  int brow = wn * 128 + rfrag;      // 0..255 span

  const size_t tStride = (size_t)64 * M;
  const u8* aP = Apk + 32 * ((size_t)M * h + (size_t)(bm * 128 + arow));

#define STG2(buf, off)                                             \
  do {                                                             \
    gload_lds16(bS + (off),          lB[buf] + tid * 16);          \
    gload_lds16(bS + (off) + rK,     lB[buf] + 4096 + tid * 16);   \
    gload_lds16(bS + (off) + 2 * rK, lB[buf] + 8192 + tid * 16);   \
    gload_lds16(bS + (off) + 3 * rK, lB[buf] + 12288 + tid * 16);  \
  } while (0)

  int NT = K >> 6;
  STG2(0, 0);
  STG2(1, 64);
  i32x8 ac0 = ld_a_g(aP);
  i32x8 ac1 = ld_a_g(aP + 1024);
  i32x8 an0 = ac0, an1 = ac1;

  for (int t = 0; t < NT; ++t) {
    int cur = t % 3;
    int nx = cur + 2; if (nx >= 3) nx -= 3;
    int kt2 = (t + 2) * 64;
    bool do_stage = (t + 2) < NT;
    bool do_pref = (t + 1) < NT;
    if (do_pref) {
      asm volatile("s_waitcnt vmcnt(8)" ::: "memory");
    } else {
      asm volatile("s_waitcnt vmcnt(0)" ::: "memory");
    }
    __builtin_amdgcn_s_barrier();   // B0 (race fix)
    // ---- single merged phase ----
    i32x8 b0 = ld_frag(lB[cur], brow, h);
    i32x8 b1 = ld_frag(lB[cur], brow + 32, h);
    i32x8 b2 = ld_frag(lB[cur], brow + 64, h);
    i32x8 b3 = ld_frag(lB[cur], brow + 96, h);
    if (do_pref) {
      const u8* ap = aP + (size_t)(t + 1) * tStride;
      an0 = ld_a_g(ap);
      an1 = ld_a_g(ap + 1024);
    }
    if (do_stage) STG2(nx, kt2);
    __builtin_amdgcn_s_barrier();
    __builtin_amdgcn_s_setprio(1);
    d00 = MFMA_MX(ac0, b0, d00);
    d10 = MFMA_MX(ac1, b0, d10);
    d01 = MFMA_MX(ac0, b1, d01);
    d11 = MFMA_MX(ac1, b1, d11);
    d02 = MFMA_MX(ac0, b2, d02);
    d12 = MFMA_MX(ac1, b2, d12);
    d03 = MFMA_MX(ac0, b3, d03);
    d13 = MFMA_MX(ac1, b3, d13);
    __builtin_amdgcn_s_setprio(0);
    ac0 = an0; ac1 = an1;
  }
#undef STG2

  float sa = 1.0f / (448.0f / fmaxf(__uint_as_float(*amax_a), 1e-12f));
  float sb = 1.0f / (448.0f / fmaxf(__uint_as_float(*amax_b), 1e-12f));
  float sc = sa * sb;

  int rb = bm * 128 + wm * 64 + h * 4;
  int cb = bn * 256 + wn * 128 + rfrag;
#pragma unroll
  for (int mi = 0; mi < 2; ++mi)
#pragma unroll
    for (int ni = 0; ni < 4; ++ni) {
      const f32x16& cc = mi ? (ni == 0 ? d10 : ni == 1 ? d11 : ni == 2 ? d12 : d13)
                            : (ni == 0 ? d00 : ni == 1 ? d01 : ni == 2 ? d02 : d03);
#pragma unroll
      for (int q = 0; q < 16; ++q) {
        int rr = rb + mi * 32 + (q & 3) + 8 * (q >> 2);
        out[(size_t)rr * N + (cb + ni * 32)] = cc[q] * sc;
      }
    }
}

// ---------------- host launcher ----------------
extern "C" void kernel_launch(void* const* d_in, const int* in_sizes, int n_in,
                              void* d_out, int out_size, void* d_ws, size_t ws_size,
                              hipStream_t stream) {
  const float* x  = (const float*)d_in[0];
  const float* w1 = (const float*)d_in[1];
  const float* v1 = (const float*)d_in[2];
  const float* w2 = (const float*)d_in[3];
  const int M = 4096, H = 4096, F = 10752;

  u8* ws = (u8*)d_ws;
  unsigned* scal = (unsigned*)ws;          // [0]=x [1]=w1 [2]=v1 [3]=w2 [4]=mid
  u8* xpk  = ws + 256;                     // packed A for gemm1 [H/32][M][32]
  u8* w1q  = xpk  + (size_t)M * H;
  u8* v1q  = w1q  + (size_t)F * H;
  u8* w2qT = v1q  + (size_t)F * H;
  u8* midpk = w2qT + (size_t)F * H;        // packed A for gemm2 [F/32][M][32]
  u16* inter = (u16*)(midpk + (size_t)M * F);  // bf16 inter

  hipMemsetAsync(scal, 0, 256, stream);
  amax4_kernel<<<2048, 256, 0, stream>>>(x, w1, v1, w2, scal);

  pack_f32_kernel<<<(M * (H / 32)) / 256, 256, 0, stream>>>(x, xpk, scal + 0, H);
  quant2_kernel<<<2048, 256, 0, stream>>>(w1, w1q, v1, v1q, scal, (size_t)F * H / 8);
  quantT_kernel<<<(F / 64) * (H / 64), 256, 0, stream>>>(w2, w2qT, scal + 3, F, H);

  gemm1_gateup<<<(M / 128) * (F / 128), 256, 0, stream>>>(xpk, w1q, v1q, scal, inter,
                                                          scal + 4, M, F, H);
  pack_bf16_kernel<<<(M * (F / 32)) / 256, 256, 0, stream>>>(inter, midpk, scal + 4, F);
  gemm2_down<<<(M / 128) * (H / 256), 256, 0, stream>>>(midpk, w2qT, scal + 4, scal + 3,
                                                        (float*)d_out, M, H, F);
}

// Round 18
// 888.073 us; speedup vs baseline: 1.4732x; 1.0064x over previous
//
#include <hip/hip_runtime.h>
#include <cstdint>
#include <cstddef>

typedef float f32x4 __attribute__((ext_vector_type(4)));
typedef float f32x16 __attribute__((ext_vector_type(16)));
typedef int i32x4 __attribute__((ext_vector_type(4)));
typedef int i32x8 __attribute__((ext_vector_type(8)));
typedef unsigned char u8;
typedef unsigned short u16;
typedef u16 u16x8 __attribute__((ext_vector_type(8)));
typedef unsigned int u32;
typedef u32 u32x4 __attribute__((ext_vector_type(4)));

// ---------------- async global->LDS (16B per lane, linear dest) ----------------
static __device__ __forceinline__ void gload_lds16(const void* g, void* l) {
  __builtin_amdgcn_global_load_lds(
      (__attribute__((address_space(1))) void*)(void*)g,
      (__attribute__((address_space(3))) void*)l,
      16, 0, 0);
}

// ---------------- fp8 e4m3fn (OCP) conversion, RNE ----------------
#if defined(__has_builtin)
#if __has_builtin(__builtin_amdgcn_cvt_pk_fp8_f32)
#define HAVE_HW_FP8 1
#endif
#endif

__device__ __forceinline__ u8 f32_to_e4m3_sw(float x) {
  unsigned s = (__float_as_uint(x) >> 24) & 0x80;
  float ax = fabsf(x);
  if (!(ax > 0.0f)) return (u8)s;
  if (ax >= 448.0f) return (u8)(s | 0x7e);
  if (ax < 0.015625f) {            // subnormal, step 2^-9
    int m = (int)rintf(ax * 512.0f);
    if (m >= 8) return (u8)(s | 0x08);
    return (u8)(s | m);
  }
  int e = ilogbf(ax);
  int m = (int)rintf(ldexpf(ax, 3 - e));
  if (m == 16) { ++e; m = 8; }
  return (u8)(s | ((e + 7) << 3) | (m - 8));
}

__device__ __forceinline__ unsigned cvt4_fp8(float a, float b, float c, float d) {
#ifdef HAVE_HW_FP8
  int lo = __builtin_amdgcn_cvt_pk_fp8_f32(a, b, 0, false);
  return (unsigned)__builtin_amdgcn_cvt_pk_fp8_f32(c, d, lo, true);
#else
  return (unsigned)f32_to_e4m3_sw(a) | ((unsigned)f32_to_e4m3_sw(b) << 8) |
         ((unsigned)f32_to_e4m3_sw(c) << 16) | ((unsigned)f32_to_e4m3_sw(d) << 24);
#endif
}

__device__ __forceinline__ float clamp448(float x) {
  return fminf(fmaxf(x, -448.f), 448.f);
}

__device__ __forceinline__ u16 f32_to_bf16(float x) {  // RNE
  unsigned u = __float_as_uint(x);
  return (u16)((u + 0x7FFFu + ((u >> 16) & 1u)) >> 16);
}

// ---------------- FUSED amax over 4 tensors (segmented grid) ----------------
__global__ __launch_bounds__(256) void amax4_kernel(const float* __restrict__ x,
                                                    const float* __restrict__ w1,
                                                    const float* __restrict__ v1,
                                                    const float* __restrict__ w2,
                                                    unsigned* __restrict__ out) {
  const size_t nX = (size_t)4096 * 4096 / 4;
  const size_t nW = (size_t)10752 * 4096 / 4;
  int b = (int)blockIdx.x;
  const f32x4* p;
  size_t n4;
  int slot, b0, nb;
  if (b < 232)       { p = (const f32x4*)x;  n4 = nX; slot = 0; b0 = 0;    nb = 232; }
  else if (b < 840)  { p = (const f32x4*)w1; n4 = nW; slot = 1; b0 = 232;  nb = 608; }
  else if (b < 1448) { p = (const f32x4*)v1; n4 = nW; slot = 2; b0 = 840;  nb = 608; }
  else               { p = (const f32x4*)w2; n4 = nW; slot = 3; b0 = 1448; nb = 600; }
  float m = 0.0f;
  size_t stride = (size_t)nb * 256;
  for (size_t i = (size_t)(b - b0) * 256 + threadIdx.x; i < n4; i += stride) {
    f32x4 v = p[i];
    m = fmaxf(m, fmaxf(fmaxf(fabsf(v[0]), fabsf(v[1])), fmaxf(fabsf(v[2]), fabsf(v[3]))));
  }
#pragma unroll
  for (int off = 32; off > 0; off >>= 1) m = fmaxf(m, __shfl_down(m, off));
  __shared__ float red[4];
  int lane = threadIdx.x & 63, wid = threadIdx.x >> 6;
  if (lane == 0) red[wid] = m;
  __syncthreads();
  if (threadIdx.x == 0) {
    float v = fmaxf(fmaxf(red[0], red[1]), fmaxf(red[2], red[3]));
    atomicMax(out + slot, __float_as_uint(v));
  }
}

// ---------------- FUSED quantize w1+v1 f32 -> fp8 (segmented grid) ----------------
__global__ __launch_bounds__(256) void quant2_kernel(const float* __restrict__ w1,
                                                     u8* __restrict__ w1q,
                                                     const float* __restrict__ v1,
                                                     u8* __restrict__ v1q,
                                                     const unsigned* __restrict__ scal,
                                                     size_t n8) {
  int b = (int)blockIdx.x;
  const f32x4* p;
  uint2* q;
  float amax;
  int rb;
  if (b < 1024) { p = (const f32x4*)w1; q = (uint2*)w1q; amax = __uint_as_float(scal[1]); rb = b; }
  else          { p = (const f32x4*)v1; q = (uint2*)v1q; amax = __uint_as_float(scal[2]); rb = b - 1024; }
  float scale = 448.0f / fmaxf(amax, 1e-12f);
  size_t stride = (size_t)1024 * 256;
  for (size_t i = (size_t)rb * 256 + threadIdx.x; i < n8; i += stride) {
    f32x4 a = p[2 * i], c = p[2 * i + 1];
    uint2 r;
    r.x = cvt4_fp8(clamp448(a[0] * scale), clamp448(a[1] * scale),
                   clamp448(a[2] * scale), clamp448(a[3] * scale));
    r.y = cvt4_fp8(clamp448(c[0] * scale), clamp448(c[1] * scale),
                   clamp448(c[2] * scale), clamp448(c[3] * scale));
    q[i] = r;
  }
}

// ---------------- pack-quantize f32 [4096][K] -> fp8 Apk[K/32][4096][32] ----------------
__global__ __launch_bounds__(256) void pack_f32_kernel(const float* __restrict__ src,
                                                       u8* __restrict__ dst,
                                                       const unsigned* __restrict__ amax_bits,
                                                       int K) {
  float amax = __uint_as_float(*amax_bits);
  float scale = 448.0f / fmaxf(amax, 1e-12f);
  int c = (int)blockIdx.x * 256 + (int)threadIdx.x;
  int m = c & 4095;
  int kb = c >> 12;
  const f32x4* s = (const f32x4*)(src + (size_t)m * K + kb * 32);
  unsigned w[8];
#pragma unroll
  for (int j = 0; j < 8; ++j) {
    f32x4 v = s[j];
    w[j] = cvt4_fp8(clamp448(v[0] * scale), clamp448(v[1] * scale),
                    clamp448(v[2] * scale), clamp448(v[3] * scale));
  }
  u32x4* d = (u32x4*)(dst + ((size_t)kb * 4096 + m) * 32);
  d[0] = u32x4{w[0], w[1], w[2], w[3]};
  d[1] = u32x4{w[4], w[5], w[6], w[7]};
}

// ---------------- pack-quantize bf16 [4096][K] -> fp8 Apk[K/32][4096][32] ----------------
__global__ __launch_bounds__(256) void pack_bf16_kernel(const u16* __restrict__ src,
                                                        u8* __restrict__ dst,
                                                        const unsigned* __restrict__ amax_bits,
                                                        int K) {
  float amax = __uint_as_float(*amax_bits);
  float scale = 448.0f / fmaxf(amax, 1e-12f);
  int c = (int)blockIdx.x * 256 + (int)threadIdx.x;
  int m = c & 4095;
  int kb = c >> 12;
  const u16x8* s = (const u16x8*)(src + (size_t)m * K + kb * 32);
  unsigned w[8];
#pragma unroll
  for (int j = 0; j < 4; ++j) {
    u16x8 v = s[j];
    float f0 = __uint_as_float((unsigned)v[0] << 16) * scale;
    float f1 = __uint_as_float((unsigned)v[1] << 16) * scale;
    float f2 = __uint_as_float((unsigned)v[2] << 16) * scale;
    float f3 = __uint_as_float((unsigned)v[3] << 16) * scale;
    float f4 = __uint_as_float((unsigned)v[4] << 16) * scale;
    float f5 = __uint_as_float((unsigned)v[5] << 16) * scale;
    float f6 = __uint_as_float((unsigned)v[6] << 16) * scale;
    float f7 = __uint_as_float((unsigned)v[7] << 16) * scale;
    w[2 * j]     = cvt4_fp8(clamp448(f0), clamp448(f1), clamp448(f2), clamp448(f3));
    w[2 * j + 1] = cvt4_fp8(clamp448(f4), clamp448(f5), clamp448(f6), clamp448(f7));
  }
  u32x4* d = (u32x4*)(dst + ((size_t)kb * 4096 + m) * 32);
  d[0] = u32x4{w[0], w[1], w[2], w[3]};
  d[1] = u32x4{w[4], w[5], w[6], w[7]};
}

// ---------------- transpose + quantize: src [R][C] f32 -> dst [C][R] fp8 ----------------
__global__ __launch_bounds__(256) void quantT_kernel(const float* __restrict__ src,
                                                     u8* __restrict__ dst,
                                                     const unsigned* __restrict__ amax_bits,
                                                     int R, int C) {
  __shared__ float t[64][65];
  float amax = __uint_as_float(*amax_bits);
  float scale = 448.0f / fmaxf(amax, 1e-12f);
  int nbr = R >> 6;
  int br = (int)blockIdx.x % nbr, bc = (int)blockIdx.x / nbr;
  int r0 = br * 64, c0 = bc * 64;
  int tid = threadIdx.x;
  int lc = tid & 63, lr = tid >> 6;
#pragma unroll
  for (int i = 0; i < 16; ++i)
    t[lr + i * 4][lc] = src[(size_t)(r0 + lr + i * 4) * C + c0 + lc];
  __syncthreads();
  int qd = tid & 15, xbase = tid >> 4;
#pragma unroll
  for (int i = 0; i < 4; ++i) {
    int x = xbase + 16 * i;  // output row index (column of src tile)
    float v0 = clamp448(t[4 * qd + 0][x] * scale);
    float v1 = clamp448(t[4 * qd + 1][x] * scale);
    float v2 = clamp448(t[4 * qd + 2][x] * scale);
    float v3 = clamp448(t[4 * qd + 3][x] * scale);
    *(unsigned*)(dst + (size_t)(c0 + x) * R + r0 + 4 * qd) = cvt4_fp8(v0, v1, v2, v3);
  }
}

// ---------------- LDS address swizzle ----------------
// 16B-block XOR within 64B row, key = (row>>2)&3 (verified conflict-free
// rounds 3-17: SQ_LDS_BANK_CONFLICT == 0).
__device__ __forceinline__ int swz_key(int r) { return (r >> 2) & 3; }

__device__ __forceinline__ int swz_off32(int r, int h) {
  return r * 64 + ((((h << 1) ^ swz_key(r)) << 4));
}

// Load a 32B MX-fp8 fragment (k-half h of row r) from a swizzled [*][64] tile.
__device__ __forceinline__ i32x8 ld_frag(const u8* base, int r, int h) {
  int o = swz_off32(r, h);
  i32x8 f;
  f.lo = *(const i32x4*)(base + o);
  f.hi = *(const i32x4*)(base + (o ^ 16));
  return f;
}

// Load a 32B packed-A fragment straight from global (coalesced).
__device__ __forceinline__ i32x8 ld_a_g(const u8* p) {
  i32x8 f;
  f.lo = *(const i32x4*)p;
  f.hi = *(const i32x4*)(p + 16);
  return f;
}

#define MFMA_MX(a, b, c) \
  __builtin_amdgcn_mfma_scale_f32_32x32x64_f8f6f4((a), (b), (c), 0, 0, 0, 0x7F7F7F7F, 0, 0x7F7F7F7F)

// ---------------- GEMM1: gate/up fused, NT, MX-fp8, BM=256 BN=64, 4 waves ----------------
// TALL-M geometry (r17 audit: LDS unit ~900cy vs matrix 1100cy per K-step was
// co-critical): per-wave 128x32 dual output = 4 M-frags (packed-A global) x
// 1 B-frag each for W and V -> B-LDS reads per MFMA halve (4 b128/wave/step),
// stage = 1 gload per mat per tile. acc = 8 x f32x16 = 128 regs (unchanged).
// Ledger: per-iter VMEM = A-pref(8) + stage(2) = 10 -> vmcnt(10); B0 after
// the wait (r9). Prologue drains vmcnt(0)+barrier (fixes r15-r17's latent
// iter-0 race where the counted wait was a no-op vs prologue stages).
__global__ __launch_bounds__(256, 2) void gemm1_gateup(
    const u8* __restrict__ Apk, const u8* __restrict__ Wq, const u8* __restrict__ Vq,
    const unsigned* __restrict__ scal, u16* __restrict__ inter,
    unsigned* __restrict__ amax_mid, int M, int N, int K) {
  __shared__ __align__(16) u8 lW[3][4096], lV[3][4096];
  __shared__ float red[4];
  int tid = threadIdx.x;
  int lane = tid & 63, wid = tid >> 6;
  int wm = wid >> 1, wn = wid & 1;  // 2M x 2N waves, per-wave 128x32 dual

  int bid = (int)blockIdx.x;
  int bm = bid & 15;                // M/256 == 16; bn-major (L2/L3 residency)
  int bn = bid >> 4;                // F/64 == 168

  int r0 = tid >> 2;                           // 0..63
  int kblk = ((tid & 3) ^ swz_key(r0)) << 4;   // pre-swizzled global source chunk
  const u8* wS = Wq + (size_t)(bn * 64 + r0) * K + kblk;
  const u8* vS = Vq + (size_t)(bn * 64 + r0) * K + kblk;

  f32x16 g0 = (f32x16)(0.f), g1 = (f32x16)(0.f), g2 = (f32x16)(0.f), g3 = (f32x16)(0.f);
  f32x16 u0 = (f32x16)(0.f), u1 = (f32x16)(0.f), u2 = (f32x16)(0.f), u3 = (f32x16)(0.f);

  int rfrag = lane & 31;
  int h = lane >> 5;
  int arow = wm * 128 + rfrag;      // A rows, 4 frags at +0/+32/+64/+96
  int brow = wn * 32 + rfrag;       // W/V rows 0..63

  const size_t tStride = (size_t)64 * M;
  const u8* aP = Apk + 32 * ((size_t)M * h + (size_t)(bm * 256 + arow));

  int NT = K >> 6;
  // prologue: stage W/V tiles 0,1 (1 gload each); A-frags tile 0; full drain.
  gload_lds16(wS + 0, lW[0] + tid * 16);
  gload_lds16(vS + 0, lV[0] + tid * 16);
  gload_lds16(wS + 64, lW[1] + tid * 16);
  gload_lds16(vS + 64, lV[1] + tid * 16);
  i32x8 ac0 = ld_a_g(aP);
  i32x8 ac1 = ld_a_g(aP + 1024);
  i32x8 ac2 = ld_a_g(aP + 2048);
  i32x8 ac3 = ld_a_g(aP + 3072);
  i32x8 an0 = ac0, an1 = ac1, an2 = ac2, an3 = ac3;
  asm volatile("s_waitcnt vmcnt(0)" ::: "memory");
  __builtin_amdgcn_s_barrier();

  for (int t = 0; t < NT; ++t) {
    int cur = t % 3;
    int nx = cur + 2; if (nx >= 3) nx -= 3;   // (t+2)%3
    int kt2 = (t + 2) * 64;
    bool do_stage = (t + 2) < NT;
    bool do_pref = (t + 1) < NT;
    if (do_pref) {
      asm volatile("s_waitcnt vmcnt(10)" ::: "memory");
    } else {
      asm volatile("s_waitcnt vmcnt(0)" ::: "memory");
    }
    __builtin_amdgcn_s_barrier();   // B0 (race fix)
    i32x8 w0 = ld_frag(lW[cur], brow, h);
    i32x8 v0 = ld_frag(lV[cur], brow, h);
    if (do_pref) {                  // packed-A prefetch for t+1 (own-wave regs)
      const u8* ap = aP + (size_t)(t + 1) * tStride;
      an0 = ld_a_g(ap);
      an1 = ld_a_g(ap + 1024);
      an2 = ld_a_g(ap + 2048);
      an3 = ld_a_g(ap + 3072);
    }
    if (do_stage) {
      gload_lds16(wS + kt2, lW[nx] + tid * 16);
      gload_lds16(vS + kt2, lV[nx] + tid * 16);
    }
    __builtin_amdgcn_s_barrier();   // B1
    __builtin_amdgcn_s_setprio(1);
    g0 = MFMA_MX(ac0, w0, g0);
    g1 = MFMA_MX(ac1, w0, g1);
    g2 = MFMA_MX(ac2, w0, g2);
    g3 = MFMA_MX(ac3, w0, g3);
    u0 = MFMA_MX(ac0, v0, u0);
    u1 = MFMA_MX(ac1, v0, u1);
    u2 = MFMA_MX(ac2, v0, u2);
    u3 = MFMA_MX(ac3, v0, u3);
    __builtin_amdgcn_s_setprio(0);
    ac0 = an0; ac1 = an1; ac2 = an2; ac3 = an3;
    // next iteration's B0 doubles as the trailing barrier
  }

  float ax = __uint_as_float(scal[0]);
  float aw = __uint_as_float(scal[1]);
  float av = __uint_as_float(scal[2]);
  float inv_x = 1.0f / (448.0f / fmaxf(ax, 1e-12f));
  float inv_w = 1.0f / (448.0f / fmaxf(aw, 1e-12f));
  float inv_v = 1.0f / (448.0f / fmaxf(av, 1e-12f));
  float sg = inv_x * inv_w, su = inv_x * inv_v;

  // C/D layout 32x32: col = lane&31, row = (reg&3) + 8*(reg>>2) + 4*(lane>>5)
  int rb = bm * 256 + wm * 128 + h * 4;
  int cb = bn * 64 + wn * 32 + rfrag;
  float lmax = 0.0f;
#pragma unroll
  for (int mi = 0; mi < 4; ++mi) {
    const f32x16& gg = mi == 0 ? g0 : mi == 1 ? g1 : mi == 2 ? g2 : g3;
    const f32x16& uu = mi == 0 ? u0 : mi == 1 ? u1 : mi == 2 ? u2 : u3;
#pragma unroll
    for (int q = 0; q < 16; ++q) {
      int rr = rb + mi * 32 + (q & 3) + 8 * (q >> 2);
      float gv = gg[q] * sg;
      float uv = uu[q] * su;
      float iv = gv / (1.0f + expf(-gv)) * uv;  // silu(g)*u
      inter[(size_t)rr * N + cb] = f32_to_bf16(iv);
      lmax = fmaxf(lmax, fabsf(iv));
    }
  }
#pragma unroll
  for (int off = 32; off > 0; off >>= 1) lmax = fmaxf(lmax, __shfl_down(lmax, off));
  if (lane == 0) red[wid] = lmax;
  __syncthreads();
  if (tid == 0)
    atomicMax(amax_mid, __float_as_uint(fmaxf(fmaxf(red[0], red[1]), fmaxf(red[2], red[3]))));
}

// ---------------- GEMM2: down proj, NT vs pre-transposed w2, BM=256 BN=128 ----------------
// Tall-M: per-wave 128x64 = 4 M-frags x 2 B-frags = 8 MFMA, acc 128 regs.
// Per-iter VMEM = A-pref(8) + stage(2) = 10 -> vmcnt(10); same ledger.
__global__ __launch_bounds__(256, 2) void gemm2_down(
    const u8* __restrict__ Apk, const u8* __restrict__ Bq,
    const unsigned* __restrict__ amax_a, const unsigned* __restrict__ amax_b,
    float* __restrict__ out, int M, int N, int K) {
  __shared__ __align__(16) u8 lB[3][8192];
  int tid = threadIdx.x;
  int lane = tid & 63, wid = tid >> 6;
  int wm = wid >> 1, wn = wid & 1;  // per-wave 128x64

  int bid = (int)blockIdx.x;
  int bm = bid & 15;                // M/256 == 16; bn-major
  int bn = bid >> 4;                // H/128 == 32

  int r0 = tid >> 2;
  int kblk = ((tid & 3) ^ swz_key(r0)) << 4;
  const u8* bS = Bq + (size_t)(bn * 128 + r0) * K + kblk;
  size_t rK = (size_t)64 * K;       // rows 64..127 (key period 16 -> same kblk)

  f32x16 d0 = (f32x16)(0.f), d1 = (f32x16)(0.f), d2 = (f32x16)(0.f), d3 = (f32x16)(0.f);
  f32x16 e0 = (f32x16)(0.f), e1 = (f32x16)(0.f), e2 = (f32x16)(0.f), e3 = (f32x16)(0.f);

  int rfrag = lane & 31;
  int h = lane >> 5;
  int arow = wm * 128 + rfrag;
  int brow = wn * 64 + rfrag;       // 0..127 span, frags at +0/+32

  const size_t tStride = (size_t)64 * M;
  const u8* aP = Apk + 32 * ((size_t)M * h + (size_t)(bm * 256 + arow));

  int NT = K >> 6;
  gload_lds16(bS + 0, lB[0] + tid * 16);
  gload_lds16(bS + 0 + rK, lB[0] + 4096 + tid * 16);
  gload_lds16(bS + 64, lB[1] + tid * 16);
  gload_lds16(bS + 64 + rK, lB[1] + 4096 + tid * 16);
  i32x8 ac0 = ld_a_g(aP);
  i32x8 ac1 = ld_a_g(aP + 1024);
  i32x8 ac2 = ld_a_g(aP + 2048);
  i32x8 ac3 = ld_a_g(aP + 3072);
  i32x8 an0 = ac0, an1 = ac1, an2 = ac2, an3 = ac3;
  asm volatile("s_waitcnt vmcnt(0)" ::: "memory");
  __builtin_amdgcn_s_barrier();

  for (int t = 0; t < NT; ++t) {
    int cur = t % 3;
    int nx = cur + 2; if (nx >= 3) nx -= 3;
    int kt2 = (t + 2) * 64;
    bool do_stage = (t + 2) < NT;
    bool do_pref = (t + 1) < NT;
    if (do_pref) {
      asm volatile("s_waitcnt vmcnt(10)" ::: "memory");
    } else {
      asm volatile("s_waitcnt vmcnt(0)" ::: "memory");
    }
    __builtin_amdgcn_s_barrier();   // B0 (race fix)
    i32x8 b0 = ld_frag(lB[cur], brow, h);
    i32x8 b1 = ld_frag(lB[cur], brow + 32, h);
    if (do_pref) {
      const u8* ap = aP + (size_t)(t + 1) * tStride;
      an0 = ld_a_g(ap);
      an1 = ld_a_g(ap + 1024);
      an2 = ld_a_g(ap + 2048);
      an3 = ld_a_g(ap + 3072);
    }
    if (do_stage) {
      gload_lds16(bS + kt2, lB[nx] + tid * 16);
      gload_lds16(bS + kt2 + rK, lB[nx] + 4096 + tid * 16);
    }
    __builtin_amdgcn_s_barrier();
    __builtin_amdgcn_s_setprio(1);
    d0 = MFMA_MX(ac0, b0, d0);
    d1 = MFMA_MX(ac1, b0, d1);
    d2 = MFMA_MX(ac2, b0, d2);
    d3 = MFMA_MX(ac3, b0, d3);
    e0 = MFMA_MX(ac0, b1, e0);
    e1 = MFMA_MX(ac1, b1, e1);
    e2 = MFMA_MX(ac2, b1, e2);
    e3 = MFMA_MX(ac3, b1, e3);
    __builtin_amdgcn_s_setprio(0);
    ac0 = an0; ac1 = an1; ac2 = an2; ac3 = an3;
  }

  float sa = 1.0f / (448.0f / fmaxf(__uint_as_float(*amax_a), 1e-12f));
  float sb = 1.0f / (448.0f / fmaxf(__uint_as_float(*amax_b), 1e-12f));
  float sc = sa * sb;

  int rb = bm * 256 + wm * 128 + h * 4;
  int cb = bn * 128 + wn * 64 + rfrag;
#pragma unroll
  for (int mi = 0; mi < 4; ++mi) {
    const f32x16& dd = mi == 0 ? d0 : mi == 1 ? d1 : mi == 2 ? d2 : d3;
    const f32x16& ee = mi == 0 ? e0 : mi == 1 ? e1 : mi == 2 ? e2 : e3;
#pragma unroll
    for (int q = 0; q < 16; ++q) {
      int rr = rb + mi * 32 + (q & 3) + 8 * (q >> 2);
      out[(size_t)rr * N + cb] = dd[q] * sc;
      out[(size_t)rr * N + cb + 32] = ee[q] * sc;
    }
  }
}

// ---------------- host launcher ----------------
extern "C" void kernel_launch(void* const* d_in, const int* in_sizes, int n_in,
                              void* d_out, int out_size, void* d_ws, size_t ws_size,
                              hipStream_t stream) {
  const float* x  = (const float*)d_in[0];
  const float* w1 = (const float*)d_in[1];
  const float* v1 = (const float*)d_in[2];
  const float* w2 = (const float*)d_in[3];
  const int M = 4096, H = 4096, F = 10752;

  u8* ws = (u8*)d_ws;
  unsigned* scal = (unsigned*)ws;          // [0]=x [1]=w1 [2]=v1 [3]=w2 [4]=mid
  u8* xpk  = ws + 256;                     // packed A for gemm1 [H/32][M][32]
  u8* w1q  = xpk  + (size_t)M * H;
  u8* v1q  = w1q  + (size_t)F * H;
  u8* w2qT = v1q  + (size_t)F * H;
  u8* midpk = w2qT + (size_t)F * H;        // packed A for gemm2 [F/32][M][32]
  u16* inter = (u16*)(midpk + (size_t)M * F);  // bf16 inter

  hipMemsetAsync(scal, 0, 256, stream);
  amax4_kernel<<<2048, 256, 0, stream>>>(x, w1, v1, w2, scal);

  pack_f32_kernel<<<(M * (H / 32)) / 256, 256, 0, stream>>>(x, xpk, scal + 0, H);
  quant2_kernel<<<2048, 256, 0, stream>>>(w1, w1q, v1, v1q, scal, (size_t)F * H / 8);
  quantT_kernel<<<(F / 64) * (H / 64), 256, 0, stream>>>(w2, w2qT, scal + 3, F, H);

  gemm1_gateup<<<(M / 256) * (F / 64), 256, 0, stream>>>(xpk, w1q, v1q, scal, inter,
                                                         scal + 4, M, F, H);
  pack_bf16_kernel<<<(M * (F / 32)) / 256, 256, 0, stream>>>(inter, midpk, scal + 4, F);
  gemm2_down<<<(M / 256) * (H / 128), 256, 0, stream>>>(midpk, w2qT, scal + 4, scal + 3,
                                                        (float*)d_out, M, H, F);
}